// Round 16
// baseline (141.136 us; speedup 1.0000x reference)
//
#include <hip/hip_runtime.h>

// ---------------------------------------------------------------------------
// MultiHeadAttention forward, MI355X/gfx950.
// cvt(weights only + mask scan) -> QKV proj FUSED fp32-A (bf16 MFMA, cvt_pk
// at fragment read, 64x64 tiles, 6 blocks/CU, XOR-swizzled LDS) -> V
// transpose -> flash attn v8 (32x32 MFMA, permlane32_swap builtin,
// pair-staged KV) -> out proj (64x64, XOR-swizzled LDS).
// ---------------------------------------------------------------------------

#define DEV static __device__ __forceinline__

typedef unsigned short u16;
typedef __attribute__((ext_vector_type(8))) short short8;
typedef __attribute__((ext_vector_type(4))) float f32x4;
typedef __attribute__((ext_vector_type(16))) float f32x16;
typedef __attribute__((ext_vector_type(4))) unsigned short ushort4v;
typedef __attribute__((ext_vector_type(4))) unsigned int uint4v;
typedef __attribute__((ext_vector_type(2))) unsigned int uint2v;

#define SEQ   2048
#define BATCH 2
#define DM    1024
#define NH    16
#define DKH   64
#define MROWS (SEQ*BATCH)   // 4096

DEV u16 f2bf(float f) {            // RNE
  union { float f; unsigned int u; } v; v.f = f;
  unsigned int u = v.u;
  return (u16)((u + 0x7FFFu + ((u >> 16) & 1u)) >> 16);
}

DEV unsigned int cvtpk_bf16(float lo, float hi) {  // dword = bf16(hi)<<16 | bf16(lo), RNE
  unsigned int r;
  asm("v_cvt_pk_bf16_f32 %0, %1, %2" : "=v"(r) : "v"(lo), "v"(hi));
  return r;
}

// swap a.lanes[32:63] <-> b.lanes[0:31] via BUILTIN (hazard-modeled; raw asm
// caused intermittent stale-register reads, r14).
#if __has_builtin(__builtin_amdgcn_permlane32_swap)
DEV void permswap(unsigned int& a, unsigned int& b) {
  uint2v r = __builtin_amdgcn_permlane32_swap(a, b, false, false);
  a = r[0]; b = r[1];
}
#else
DEV void permswap(unsigned int& a, unsigned int& b) {
  asm volatile("s_nop 1\n\tv_permlane32_swap_b32 %0, %1\n\ts_nop 1"
               : "+v"(a), "+v"(b));
}
#endif

#if __has_builtin(__builtin_amdgcn_exp2f)
#define EXP2(x) __builtin_amdgcn_exp2f(x)
#else
#define EXP2(x) exp2f(x)
#endif

// async global->LDS, 16B per lane. LDS dest is wave-uniform base + lane*16.
DEV void async16(const void* g, void* l) {
  __builtin_amdgcn_global_load_lds(
      (const __attribute__((address_space(1))) unsigned int*)g,
      (__attribute__((address_space(3))) unsigned int*)l, 16, 0, 0);
}

// ---------------------------------------------------------------------------
// fp32 -> bf16 conversion: weights only (d==nullptr entry = mask-zero scan)
// ---------------------------------------------------------------------------
struct CvtArgs {
  const float* s[8];
  u16* d[8];
  int n[8];
  float scale[8];
  int* flag;
};

__global__ __launch_bounds__(256) void cvt_kernel(CvtArgs a) {
  const int t = blockIdx.y;
  const int n = a.n[t];
  const int stride = 1024 * 256 * 4;
  if (a.d[t] == nullptr) {   // mask scan
    const float* __restrict__ m = a.s[t];
    int any = 0;
    for (int i = (blockIdx.x * 256 + threadIdx.x) * 4; i < n; i += stride) {
      f32x4 v = *(const f32x4*)&m[i];
      any |= (v[0] != 0.f); any |= (v[1] != 0.f);
      any |= (v[2] != 0.f); any |= (v[3] != 0.f);
    }
    if (any) atomicOr(a.flag, 1);
    return;
  }
  const float* __restrict__ s = a.s[t];
  u16* __restrict__ d = a.d[t];
  const float sc = a.scale[t];
  for (int i = (blockIdx.x * 256 + threadIdx.x) * 4; i < n; i += stride) {
    f32x4 f = *(const f32x4*)&s[i];
    ushort4v o;
    o[0] = f2bf(f[0] * sc); o[1] = f2bf(f[1] * sc);
    o[2] = f2bf(f[2] * sc); o[3] = f2bf(f[3] * sc);
    *(ushort4v*)&d[i] = o;
  }
}

// ---------------------------------------------------------------------------
// Fused QKV GEMM: C[M,N] = bf16(A_f32)[M,K] @ W[N,K]^T + bias*bscale.
// 64x64 tiles (per-wave 32x32), BK=64, 24 KB LDS -> 6 blocks/CU, grid
// (64,16,3)=3072.  A staged fp32 (256B rows), W bf16 (128B rows), both
// XOR-swizzled both-sides (rule #21).  cvt_pk at A-fragment read.
// ---------------------------------------------------------------------------
struct QkvArgs {
  const float* A[3];
  const u16* W[3];
  const float* bias[3];
  float bscale[3];
  u16* C[3];
};

__global__ __launch_bounds__(256) void gemm_qkvf_kernel(QkvArgs p, int M, int N, int K) {
  __shared__ float Asf[64 * 64];   // 16 KB fp32 A tile, 256B rows, swizzled
  __shared__ u16 Bs[64 * 64];      // 8 KB bf16 W tile, 128B rows, swizzled
  const int z = blockIdx.z;
  const float* __restrict__ A = p.A[z];
  const u16* __restrict__ W = p.W[z];
  const int fl = blockIdx.x + 64 * blockIdx.y;           // 0..1023
  const int virt = (fl & 7) * 128 + (fl >> 3);           // bijective XCD swizzle
  const int mb = virt >> 4, nb = virt & 15;
  const int m0 = mb * 64, n0 = nb * 64;

  const int tid = threadIdx.x;
  const int lane = tid & 63;
  const int wid = tid >> 6;
  const int wr = wid >> 1, wc = wid & 1;
  const int sr = lane & 15, g = lane >> 4;
  const int sws = (sr & 7) << 4;     // fragment-read swizzle

  f32x4 acc[2][2] = {};

  // A staging: subtile = 16 rows x 256B; flat byte = it*4096 + tid*16
  const int arow_a = tid >> 4;                                   // 0..15
  const int acolb_a = ((tid & 15) * 16) ^ ((arow_a & 7) << 4);   // swizzled byte col
  // B staging: subtile = 32 rows x 128B
  const int brow = tid >> 3;                                     // 0..31
  const int bcolb = ((tid & 7) * 16) ^ ((brow & 7) << 4);

  for (int kt = 0; kt < K; kt += 64) {
#pragma unroll
    for (int it = 0; it < 4; ++it)
      async16(A + (size_t)(m0 + it * 16 + arow_a) * K + kt + (acolb_a >> 2),
              (char*)Asf + it * 4096 + wid * 1024);
#pragma unroll
    for (int j = 0; j < 2; ++j)
      async16(W + (size_t)(n0 + j * 32 + brow) * K + kt + (bcolb >> 1),
              (char*)Bs + j * 4096 + wid * 1024);
    __syncthreads();
#pragma unroll
    for (int kk = 0; kk < 2; ++kk) {
      short8 af[2], bf[2];
#pragma unroll
      for (int mt = 0; mt < 2; ++mt) {
        const char* ap = (const char*)Asf + (wr * 32 + mt * 16 + sr) * 256;
        const int c0 = kk * 128 + g * 32;
        f32x4 a0 = *(const f32x4*)(ap + (c0 ^ sws));
        f32x4 a1 = *(const f32x4*)(ap + ((c0 + 16) ^ sws));
        union { uint4v u; short8 s; } ca_;
        ca_.u[0] = cvtpk_bf16(a0[0], a0[1]);
        ca_.u[1] = cvtpk_bf16(a0[2], a0[3]);
        ca_.u[2] = cvtpk_bf16(a1[0], a1[1]);
        ca_.u[3] = cvtpk_bf16(a1[2], a1[3]);
        af[mt] = ca_.s;
      }
#pragma unroll
      for (int nt = 0; nt < 2; ++nt)
        bf[nt] = *(const short8*)((const char*)Bs + (wc * 32 + nt * 16 + sr) * 128 +
                                  ((kk * 64 + g * 16) ^ sws));
#pragma unroll
      for (int mt = 0; mt < 2; ++mt)
#pragma unroll
        for (int nt = 0; nt < 2; ++nt)
          acc[mt][nt] = __builtin_amdgcn_mfma_f32_16x16x32_bf16(af[mt], bf[nt], acc[mt][nt], 0, 0, 0);
    }
    __syncthreads();
  }

  // C/D layout: row=(lane>>4)*4+reg, col=lane&15  [m89-verified]
  const float* __restrict__ bias = p.bias[z];
  const float bscale = p.bscale[z];
  u16* __restrict__ C = p.C[z];
#pragma unroll
  for (int nt = 0; nt < 2; ++nt) {
    const int col = n0 + wc * 32 + nt * 16 + sr;
    const float bv = bias[col] * bscale;
#pragma unroll
    for (int mt = 0; mt < 2; ++mt)
#pragma unroll
      for (int r = 0; r < 4; ++r) {
        const int row = m0 + wr * 32 + mt * 16 + g * 4 + r;
        C[(size_t)row * N + col] = f2bf(acc[mt][nt][r] + bv);
      }
  }
}

// ---------------------------------------------------------------------------
// Out-proj GEMM (bf16 A x bf16 W^T -> fp32 + bias).  64x64 tiles (MT=NT=2),
// grid 1024 = 4 blocks/CU, 16 KB LDS, XOR-swizzled tiles.
// ---------------------------------------------------------------------------
__global__ __launch_bounds__(256) void gemm_f32_kernel(const u16* __restrict__ A,
                                                       const u16* __restrict__ W,
                                                       const float* __restrict__ bias,
                                                       float* __restrict__ C,
                                                       int M, int N, int K) {
  __shared__ u16 As[64 * 64];
  __shared__ u16 Bs[64 * 64];
  const int fl = blockIdx.x + 64 * blockIdx.y;
  const int virt = (fl & 7) * 128 + (fl >> 3);
  const int mb = virt >> 4, nb = virt & 15;
  const int m0 = mb * 64, n0 = nb * 64;

  const int tid = threadIdx.x;
  const int lane = tid & 63;
  const int wid = tid >> 6;
  const int wr = wid >> 1, wc = wid & 1;
  const int sr = lane & 15, g = lane >> 4;
  const int sws = (sr & 7) << 4;

  f32x4 acc[2][2] = {};

  const int arow = tid >> 3;                                  // 0..31
  const int acolb = ((tid & 7) * 16) ^ ((arow & 7) << 4);     // swizzled byte col

  for (int kt = 0; kt < K; kt += 64) {
#pragma unroll
    for (int j = 0; j < 2; ++j) {
      async16(A + (size_t)(m0 + j * 32 + arow) * K + kt + (acolb >> 1),
              (char*)As + j * 4096 + wid * 1024);
      async16(W + (size_t)(n0 + j * 32 + arow) * K + kt + (acolb >> 1),
              (char*)Bs + j * 4096 + wid * 1024);
    }
    __syncthreads();
#pragma unroll
    for (int kk = 0; kk < 2; ++kk) {
      short8 af[2], bf[2];
#pragma unroll
      for (int mt = 0; mt < 2; ++mt)
        af[mt] = *(const short8*)((const char*)As + (wr * 32 + mt * 16 + sr) * 128 +
                                  ((kk * 64 + g * 16) ^ sws));
#pragma unroll
      for (int nt = 0; nt < 2; ++nt)
        bf[nt] = *(const short8*)((const char*)Bs + (wc * 32 + nt * 16 + sr) * 128 +
                                  ((kk * 64 + g * 16) ^ sws));
#pragma unroll
      for (int mt = 0; mt < 2; ++mt)
#pragma unroll
        for (int nt = 0; nt < 2; ++nt)
          acc[mt][nt] = __builtin_amdgcn_mfma_f32_16x16x32_bf16(af[mt], bf[nt], acc[mt][nt], 0, 0, 0);
    }
    __syncthreads();
  }

#pragma unroll
  for (int nt = 0; nt < 2; ++nt) {
    const int col = n0 + wc * 32 + nt * 16 + sr;
    const float bv = bias[col];
#pragma unroll
    for (int mt = 0; mt < 2; ++mt)
#pragma unroll
      for (int r = 0; r < 4; ++r) {
        const int row = m0 + wr * 32 + mt * 16 + g * 4 + r;
        C[(size_t)row * N + col] = acc[mt][nt][r] + bv;
      }
  }
}

// ---------------------------------------------------------------------------
// V transpose: Vh (S,B,D) bf16 -> VT[bh][dk][t]  (shape [32][64][2048])
// ---------------------------------------------------------------------------
__global__ __launch_bounds__(256) void vtrans_kernel(const u16* __restrict__ Vh,
                                                     u16* __restrict__ VT) {
  __shared__ u16 tl[4096];   // [t][dk] linear
  const int tid = threadIdx.x;
  const int w = tid >> 6;
  const int t0 = blockIdx.x * 64;
  const int bh = blockIdx.y;
  const int b = bh >> 4, h = bh & 15;
  const int str = tid >> 3;
  const int scc = (tid & 7) * 8;
#pragma unroll
  for (int it = 0; it < 2; ++it)
    async16(Vh + (size_t)((t0 + str + it * 32) * 2 + b) * 1024 + h * 64 + scc,
            (char*)tl + it * 4096 + w * 1024);
  __syncthreads();
  const int dk = tid >> 2;
  const int t4 = (tid & 3) * 16;
  short8 ov[2];
#pragma unroll
  for (int half = 0; half < 2; ++half)
#pragma unroll
    for (int j = 0; j < 8; ++j)
      ov[half][j] = (short)tl[(t4 + half * 8 + j) * 64 + dk];
  u16* dst = VT + (size_t)(bh * 64 + dk) * 2048 + t0 + t4;
  *(short8*)dst = ov[0];
  *(short8*)(dst + 8) = ov[1];
}

// ---------------------------------------------------------------------------
// Flash attention v8 (best found): 32x32x16 MFMA, pair-staged KV.  Grid 512
// flat (XCD-swizzled), 256 thr = 4 waves, wave owns 32 q-rows.  TWO 64-row
// KV tiles staged per barrier (4 LDS buffers, 64 KB); both processed between
// barriers for ILP.  Swapped QK^T (A=K, B=Q, 0.125*log2e in Wq); C/D col=q=
// lane&31, row t=(r&3)+8*(r>>2)+4*(lane>>5) [m74/m101].  P->PV A-frags via
// cvt_pk + permlane32_swap builtin.  No-max softmax, l reduced at end.
// ---------------------------------------------------------------------------
__global__ __launch_bounds__(256, 2) void attn8_kernel(const u16* __restrict__ Q,
                                                       const u16* __restrict__ K,
                                                       const u16* __restrict__ VT,
                                                       const float* __restrict__ mask,
                                                       const int* __restrict__ maskflag,
                                                       u16* __restrict__ O) {
  __shared__ u16 Kl[2][2][4096];   // [buf][subtile][t 0..63][d 0..63], swizzled
  __shared__ u16 Vl[2][2][4096];   // [buf][subtile][d 0..63][t 0..63], swizzled

  const int tid = threadIdx.x;
  const int lane = tid & 63;
  const int w = tid >> 6;
  const int ln = lane & 31;     // col within 32-block
  const int hi = lane >> 5;     // lane half
  const int sw = (ln & 7) << 4;

  // T1: cluster the 16 q-blocks of each bh on one XCD (512 = 8 XCDs x 64)
  const int flat = blockIdx.x;
  const int virt = ((flat & 7) << 6) | (flat >> 3);
  const int qi = virt & 15;
  const int bh = virt >> 4;
  const int q0 = qi * 128 + w * 32;
  const int b = bh >> 4, h = bh & 15;
  const int usemask = *maskflag;

  const u16* Qb = Q + b * DM + h * DKH;
  const u16* Kb = K + b * DM + h * DKH;
  const u16* VTb = VT + (size_t)bh * 64 * 2048;

  // Q fragments (B-operand 32x32x16: col n=q=ln, k = ks*16 + hi*8 + j)
  short8 aq[4];
#pragma unroll
  for (int ks = 0; ks < 4; ++ks)
    aq[ks] = *(const short8*)&Qb[(size_t)(q0 + ln) * 2048 + ks * 16 + hi * 8];

  f32x16 acc[2] = {};
  float l_ = 0.f;
  const float L2E = 1.44269504088896f;

  const int strow = tid >> 3;                                   // 0..31
  const int scb = (((tid & 7) * 16) ^ ((strow & 7) << 4)) >> 1; // pre-swizzled col (elems)

  auto STAGE = [&](int nb, int t0n) {   // stages rows [t0n, t0n+128)
#pragma unroll
    for (int st = 0; st < 2; ++st)
#pragma unroll
      for (int it = 0; it < 2; ++it) {
        async16(Kb + (size_t)(t0n + st * 64 + strow + it * 32) * 2048 + scb,
                (char*)&Kl[nb][st][0] + it * 4096 + w * 1024);
        async16(VTb + (size_t)(strow + it * 32) * 2048 + t0n + st * 64 + scb,
                (char*)&Vl[nb][st][0] + it * 4096 + w * 1024);
      }
  };

  STAGE(0, 0);
  __syncthreads();
  int cur = 0;

  for (int tp = 0; tp < SEQ; tp += 128) {
    if (tp + 128 < SEQ) STAGE(cur ^ 1, tp + 128);

#pragma unroll
    for (int st = 0; st < 2; ++st) {
      const int t0 = tp + st * 64;

      // K fragments (A-operand: row t = tb*32+ln, k = d = ks*16+hi*8+j)
      short8 kf[2][4];
#pragma unroll
      for (int tb = 0; tb < 2; ++tb)
#pragma unroll
        for (int ks = 0; ks < 4; ++ks)
          kf[tb][ks] = *(const short8*)((const char*)&Kl[cur][st][0] +
                                        (tb * 32 + ln) * 128 + ((ks * 32 + hi * 16) ^ sw));

      // S'^T (log2 units): 2 blocks of 32t x 32q
      f32x16 sc[2] = {};
      __builtin_amdgcn_s_setprio(1);
#pragma unroll
      for (int tb = 0; tb < 2; ++tb)
#pragma unroll
        for (int ks = 0; ks < 4; ++ks)
          sc[tb] = __builtin_amdgcn_mfma_f32_32x32x16_bf16(kf[tb][ks], aq[ks], sc[tb], 0, 0, 0);
      __builtin_amdgcn_s_setprio(0);

      // V^T fragments (B-operand: col n=d=db*32+ln, k = t = ks*16+hi*8+j)
      short8 vf[2][4];
#pragma unroll
      for (int db = 0; db < 2; ++db)
#pragma unroll
        for (int ks = 0; ks < 4; ++ks)
          vf[db][ks] = *(const short8*)((const char*)&Vl[cur][st][0] +
                                        (db * 32 + ln) * 128 + ((ks * 32 + hi * 16) ^ sw));

      // no-max softmax + in-register P redistribution (cvt_pk + permlane32_swap)
      short8 pa[4];
      float rs = 0.f;
#pragma unroll
      for (int tb = 0; tb < 2; ++tb) {
        float p[16];
#pragma unroll
        for (int r = 0; r < 16; ++r) {
          float xv = sc[tb][r];
          if (usemask)
            xv = __builtin_fmaf(
                mask[(size_t)(q0 + ln) * SEQ + t0 + tb * 32 + (r & 3) + 8 * (r >> 2) + 4 * hi],
                L2E, xv);
          p[r] = EXP2(xv);
          rs += p[r];
        }
#pragma unroll
        for (int ksl = 0; ksl < 2; ++ksl) {
          unsigned int c0 = cvtpk_bf16(p[8 * ksl + 0], p[8 * ksl + 1]);  // (t0,t1 | t4,t5)
          unsigned int c1 = cvtpk_bf16(p[8 * ksl + 2], p[8 * ksl + 3]);  // (t2,t3 | t6,t7)
          unsigned int c4 = cvtpk_bf16(p[8 * ksl + 4], p[8 * ksl + 5]);  // (t8,t9 | t12,t13)
          unsigned int c5 = cvtpk_bf16(p[8 * ksl + 6], p[8 * ksl + 7]);  // (t10,t11|t14,t15)
          permswap(c0, c4);   // c0 -> dword0; c4 -> dword2
          permswap(c1, c5);   // c1 -> dword1; c5 -> dword3
          union { uint4v u; short8 s; } cc;
          cc.u[0] = c0; cc.u[1] = c1; cc.u[2] = c4; cc.u[3] = c5;
          pa[tb * 2 + ksl] = cc.s;
        }
      }
      l_ += rs;

      // PV: O[q][d] += P[q][t] V[t][d]
      __builtin_amdgcn_s_setprio(1);
#pragma unroll
      for (int ks = 0; ks < 4; ++ks)
#pragma unroll
        for (int db = 0; db < 2; ++db)
          acc[db] = __builtin_amdgcn_mfma_f32_32x32x16_bf16(pa[ks], vf[db][ks], acc[db], 0, 0, 0);
      __builtin_amdgcn_s_setprio(0);
    }

    __syncthreads();
    cur ^= 1;
  }

  // final l reduction (halves) + normalize + write
  l_ += __shfl_xor(l_, 32);
  const float linv = 1.f / l_;
  float lb[16];
#pragma unroll
  for (int r = 0; r < 16; ++r)
    lb[r] = __shfl(linv, (r & 3) + 8 * (r >> 2) + 4 * hi);
  const size_t obase = (size_t)b * DM + h * DKH;
#pragma unroll
  for (int db = 0; db < 2; ++db)
#pragma unroll
    for (int r = 0; r < 16; ++r) {
      const int q = q0 + (r & 3) + 8 * (r >> 2) + 4 * hi;
      O[(size_t)q * 2048 + obase + db * 32 + ln] = f2bf(acc[db][r] * lb[r]);
    }
}

// ---------------------------------------------------------------------------
// Launch
// ---------------------------------------------------------------------------
extern "C" void kernel_launch(void* const* d_in, const int* in_sizes, int n_in,
                              void* d_out, int out_size, void* d_ws, size_t ws_size,
                              hipStream_t stream) {
  const float* q = (const float*)d_in[0];
  const float* k = (const float*)d_in[1];
  const float* v = (const float*)d_in[2];
  const float* msk = (const float*)d_in[3];
  const float* Wq = (const float*)d_in[4];
  const float* bq = (const float*)d_in[5];
  const float* Wk = (const float*)d_in[6];
  const float* bk = (const float*)d_in[7];
  const float* Wv = (const float*)d_in[8];
  const float* bv = (const float*)d_in[9];
  const float* Wo = (const float*)d_in[10];
  const float* bo = (const float*)d_in[11];
  float* out = (float*)d_out;

  char* ws = (char*)d_ws;
  const size_t SZX = (size_t)MROWS * DM * 2;   // 8 MB bf16 activation
  const size_t SZW = (size_t)DM * DM * 2;      // 2 MB bf16 weight
  u16* Wqb = (u16*)(ws + 3 * SZX + 0 * SZW);
  u16* Wkb = (u16*)(ws + 3 * SZX + 1 * SZW);
  u16* Wvb = (u16*)(ws + 3 * SZX + 2 * SZW);
  u16* Wob = (u16*)(ws + 3 * SZX + 3 * SZW);
  u16* Qh  = (u16*)(ws + 3 * SZX + 4 * SZW + 0 * SZX);
  u16* Kh  = (u16*)(ws + 3 * SZX + 4 * SZW + 1 * SZX);
  u16* Vh  = (u16*)(ws + 3 * SZX + 4 * SZW + 2 * SZX);
  u16* AO  = (u16*)(ws + 3 * SZX + 4 * SZW + 3 * SZX);
  int* flag = (int*)(ws + 7 * SZX + 4 * SZW);
  u16* VTg = (u16*)(ws + 0 * SZX);   // free region (old qb slot)

  hipMemsetAsync(flag, 0, 4, stream);

  // fold softmax scale AND log2(e) into Wq/bq: S' = (QK^T)/8 * log2e
  const float QS = 0.125f * 1.44269504088896f;

  CvtArgs ca = {};
  ca.s[0] = Wq; ca.d[0] = Wqb; ca.n[0] = DM * DM;    ca.scale[0] = QS;
  ca.s[1] = Wk; ca.d[1] = Wkb; ca.n[1] = DM * DM;    ca.scale[1] = 1.f;
  ca.s[2] = Wv; ca.d[2] = Wvb; ca.n[2] = DM * DM;    ca.scale[2] = 1.f;
  ca.s[3] = Wo; ca.d[3] = Wob; ca.n[3] = DM * DM;    ca.scale[3] = 1.f;
  ca.s[4] = msk; ca.d[4] = nullptr; ca.n[4] = SEQ * SEQ; ca.scale[4] = 1.f;
  ca.flag = flag;
  cvt_kernel<<<dim3(1024, 5, 1), 256, 0, stream>>>(ca);

  QkvArgs gp;
  gp.A[0] = q; gp.W[0] = Wqb; gp.bias[0] = bq; gp.bscale[0] = QS;  gp.C[0] = Qh;
  gp.A[1] = k; gp.W[1] = Wkb; gp.bias[1] = bk; gp.bscale[1] = 1.f; gp.C[1] = Kh;
  gp.A[2] = v; gp.W[2] = Wvb; gp.bias[2] = bv; gp.bscale[2] = 1.f; gp.C[2] = Vh;
  gemm_qkvf_kernel<<<dim3(64, 16, 3), 256, 0, stream>>>(gp, MROWS, DM, DM);

  vtrans_kernel<<<dim3(32, 32, 1), 256, 0, stream>>>(Vh, VTg);

  attn8_kernel<<<dim3(512, 1, 1), 256, 0, stream>>>(Qh, Kh, VTg, msk, flag, AO);

  gemm_f32_kernel<<<dim3(64, 16, 1), 256, 0, stream>>>(AO, Wob, bo, out, MROWS, DM, DM);
}

// Round 17
// 141.036 us; speedup vs baseline: 1.0007x; 1.0007x over previous
//
#include <hip/hip_runtime.h>

// ---------------------------------------------------------------------------
// MultiHeadAttention forward, MI355X/gfx950.
// cvt(weights only + mask scan) -> QKV proj FUSED fp32-A (bf16 MFMA, cvt_pk
// at fragment read, 64x128 tiles, DOUBLE-BUFFERED staging, XOR-swizzled LDS)
// -> V transpose -> flash attn v8 (32x32 MFMA, permlane32_swap builtin,
// pair-staged KV) -> out proj (64x64, dbuf staging, XOR-swizzled LDS).
// ---------------------------------------------------------------------------

#define DEV static __device__ __forceinline__

typedef unsigned short u16;
typedef __attribute__((ext_vector_type(8))) short short8;
typedef __attribute__((ext_vector_type(4))) float f32x4;
typedef __attribute__((ext_vector_type(16))) float f32x16;
typedef __attribute__((ext_vector_type(4))) unsigned short ushort4v;
typedef __attribute__((ext_vector_type(4))) unsigned int uint4v;
typedef __attribute__((ext_vector_type(2))) unsigned int uint2v;

#define SEQ   2048
#define BATCH 2
#define DM    1024
#define NH    16
#define DKH   64
#define MROWS (SEQ*BATCH)   // 4096

DEV u16 f2bf(float f) {            // RNE
  union { float f; unsigned int u; } v; v.f = f;
  unsigned int u = v.u;
  return (u16)((u + 0x7FFFu + ((u >> 16) & 1u)) >> 16);
}

DEV unsigned int cvtpk_bf16(float lo, float hi) {  // dword = bf16(hi)<<16 | bf16(lo), RNE
  unsigned int r;
  asm("v_cvt_pk_bf16_f32 %0, %1, %2" : "=v"(r) : "v"(lo), "v"(hi));
  return r;
}

// swap a.lanes[32:63] <-> b.lanes[0:31] via BUILTIN (hazard-modeled; raw asm
// caused intermittent stale-register reads, r14).
#if __has_builtin(__builtin_amdgcn_permlane32_swap)
DEV void permswap(unsigned int& a, unsigned int& b) {
  uint2v r = __builtin_amdgcn_permlane32_swap(a, b, false, false);
  a = r[0]; b = r[1];
}
#else
DEV void permswap(unsigned int& a, unsigned int& b) {
  asm volatile("s_nop 1\n\tv_permlane32_swap_b32 %0, %1\n\ts_nop 1"
               : "+v"(a), "+v"(b));
}
#endif

#if __has_builtin(__builtin_amdgcn_exp2f)
#define EXP2(x) __builtin_amdgcn_exp2f(x)
#else
#define EXP2(x) exp2f(x)
#endif

// async global->LDS, 16B per lane. LDS dest is wave-uniform base + lane*16.
DEV void async16(const void* g, void* l) {
  __builtin_amdgcn_global_load_lds(
      (const __attribute__((address_space(1))) unsigned int*)g,
      (__attribute__((address_space(3))) unsigned int*)l, 16, 0, 0);
}

// ---------------------------------------------------------------------------
// fp32 -> bf16 conversion: weights only (d==nullptr entry = mask-zero scan)
// ---------------------------------------------------------------------------
struct CvtArgs {
  const float* s[8];
  u16* d[8];
  int n[8];
  float scale[8];
  int* flag;
};

__global__ __launch_bounds__(256) void cvt_kernel(CvtArgs a) {
  const int t = blockIdx.y;
  const int n = a.n[t];
  const int stride = 1024 * 256 * 4;
  if (a.d[t] == nullptr) {   // mask scan
    const float* __restrict__ m = a.s[t];
    int any = 0;
    for (int i = (blockIdx.x * 256 + threadIdx.x) * 4; i < n; i += stride) {
      f32x4 v = *(const f32x4*)&m[i];
      any |= (v[0] != 0.f); any |= (v[1] != 0.f);
      any |= (v[2] != 0.f); any |= (v[3] != 0.f);
    }
    if (any) atomicOr(a.flag, 1);
    return;
  }
  const float* __restrict__ s = a.s[t];
  u16* __restrict__ d = a.d[t];
  const float sc = a.scale[t];
  for (int i = (blockIdx.x * 256 + threadIdx.x) * 4; i < n; i += stride) {
    f32x4 f = *(const f32x4*)&s[i];
    ushort4v o;
    o[0] = f2bf(f[0] * sc); o[1] = f2bf(f[1] * sc);
    o[2] = f2bf(f[2] * sc); o[3] = f2bf(f[3] * sc);
    *(ushort4v*)&d[i] = o;
  }
}

// ---------------------------------------------------------------------------
// Fused QKV GEMM: C[M,N] = bf16(A_f32)[M,K] @ W[N,K]^T + bias*bscale.
// 64x128 tiles, BK=64, DOUBLE-BUFFERED staging (64 KB LDS, 2 blocks/CU):
// STAGE(next K-tile) issued BEFORE compute(cur) so the global->LDS latency
// hides under ~16 MFMA + LDS reads (attn8's proven pattern).  A fp32 (256B
// rows) + W bf16 (128B rows), both XOR-swizzled both-sides (rule #21).
// cvt_pk at A-fragment read.
// ---------------------------------------------------------------------------
struct QkvArgs {
  const float* A[3];
  const u16* W[3];
  const float* bias[3];
  float bscale[3];
  u16* C[3];
};

__global__ __launch_bounds__(256) void gemm_qkvf_kernel(QkvArgs p, int M, int N, int K) {
  __shared__ float Asf[2][64 * 64];   // 2 x 16 KB fp32 A tiles, swizzled
  __shared__ u16 Bs[2][128 * 64];     // 2 x 16 KB bf16 W tiles, swizzled
  const int z = blockIdx.z;
  const float* __restrict__ A = p.A[z];
  const u16* __restrict__ W = p.W[z];
  const int fl = blockIdx.x + 64 * blockIdx.y;
  const int virt = (fl & 7) * 64 + (fl >> 3);
  const int mb = virt >> 3, nb = virt & 7;
  const int m0 = mb * 64, n0 = nb * 128;

  const int tid = threadIdx.x;
  const int lane = tid & 63;
  const int wid = tid >> 6;
  const int wr = wid >> 1, wc = wid & 1;
  const int sr = lane & 15, g = lane >> 4;
  const int sws = (sr & 7) << 4;     // fragment-read swizzle

  f32x4 acc[2][4] = {};

  // A staging: subtile = 16 rows x 256B; flat byte = it*4096 + tid*16
  const int arow_a = tid >> 4;                                   // 0..15
  const int acolb_a = ((tid & 15) * 16) ^ ((arow_a & 7) << 4);   // swizzled byte col
  // B staging: subtile = 32 rows x 128B
  const int brow = tid >> 3;                                     // 0..31
  const int bcolb = ((tid & 7) * 16) ^ ((brow & 7) << 4);

  auto STAGE = [&](int nb_, int kt) {
#pragma unroll
    for (int it = 0; it < 4; ++it)
      async16(A + (size_t)(m0 + it * 16 + arow_a) * K + kt + (acolb_a >> 2),
              (char*)&Asf[nb_][0] + it * 4096 + wid * 1024);
#pragma unroll
    for (int j = 0; j < 4; ++j)
      async16(W + (size_t)(n0 + j * 32 + brow) * K + kt + (bcolb >> 1),
              (char*)&Bs[nb_][0] + j * 4096 + wid * 1024);
  };

  STAGE(0, 0);
  __syncthreads();
  int cur = 0;

  for (int kt = 0; kt < K; kt += 64) {
    if (kt + 64 < K) STAGE(cur ^ 1, kt + 64);
#pragma unroll
    for (int kk = 0; kk < 2; ++kk) {
      short8 af[2], bf[4];
#pragma unroll
      for (int mt = 0; mt < 2; ++mt) {
        const char* ap = (const char*)&Asf[cur][0] + (wr * 32 + mt * 16 + sr) * 256;
        const int c0 = kk * 128 + g * 32;
        f32x4 a0 = *(const f32x4*)(ap + (c0 ^ sws));
        f32x4 a1 = *(const f32x4*)(ap + ((c0 + 16) ^ sws));
        union { uint4v u; short8 s; } ca_;
        ca_.u[0] = cvtpk_bf16(a0[0], a0[1]);
        ca_.u[1] = cvtpk_bf16(a0[2], a0[3]);
        ca_.u[2] = cvtpk_bf16(a1[0], a1[1]);
        ca_.u[3] = cvtpk_bf16(a1[2], a1[3]);
        af[mt] = ca_.s;
      }
#pragma unroll
      for (int nt = 0; nt < 4; ++nt)
        bf[nt] = *(const short8*)((const char*)&Bs[cur][0] + (wc * 64 + nt * 16 + sr) * 128 +
                                  ((kk * 64 + g * 16) ^ sws));
#pragma unroll
      for (int mt = 0; mt < 2; ++mt)
#pragma unroll
        for (int nt = 0; nt < 4; ++nt)
          acc[mt][nt] = __builtin_amdgcn_mfma_f32_16x16x32_bf16(af[mt], bf[nt], acc[mt][nt], 0, 0, 0);
    }
    __syncthreads();   // waves done with buf[cur]; prefetch of buf[cur^1] drained
    cur ^= 1;
  }

  // C/D layout: row=(lane>>4)*4+reg, col=lane&15  [m89-verified]
  const float* __restrict__ bias = p.bias[z];
  const float bscale = p.bscale[z];
  u16* __restrict__ C = p.C[z];
#pragma unroll
  for (int nt = 0; nt < 4; ++nt) {
    const int col = n0 + wc * 64 + nt * 16 + sr;
    const float bv = bias[col] * bscale;
#pragma unroll
    for (int mt = 0; mt < 2; ++mt)
#pragma unroll
      for (int r = 0; r < 4; ++r) {
        const int row = m0 + wr * 32 + mt * 16 + g * 4 + r;
        C[(size_t)row * N + col] = f2bf(acc[mt][nt][r] + bv);
      }
  }
}

// ---------------------------------------------------------------------------
// Out-proj GEMM (bf16 A x bf16 W^T -> fp32 + bias).  64x64 tiles (MT=NT=2),
// grid 1024, DOUBLE-BUFFERED staging (32 KB LDS, 5 blocks/CU), XOR-swizzled.
// ---------------------------------------------------------------------------
__global__ __launch_bounds__(256) void gemm_f32_kernel(const u16* __restrict__ A,
                                                       const u16* __restrict__ W,
                                                       const float* __restrict__ bias,
                                                       float* __restrict__ C,
                                                       int M, int N, int K) {
  __shared__ u16 As[2][64 * 64];
  __shared__ u16 Bs[2][64 * 64];
  const int fl = blockIdx.x + 64 * blockIdx.y;
  const int virt = (fl & 7) * 128 + (fl >> 3);
  const int mb = virt >> 4, nb = virt & 15;
  const int m0 = mb * 64, n0 = nb * 64;

  const int tid = threadIdx.x;
  const int lane = tid & 63;
  const int wid = tid >> 6;
  const int wr = wid >> 1, wc = wid & 1;
  const int sr = lane & 15, g = lane >> 4;
  const int sws = (sr & 7) << 4;

  f32x4 acc[2][2] = {};

  const int arow = tid >> 3;                                  // 0..31
  const int acolb = ((tid & 7) * 16) ^ ((arow & 7) << 4);     // swizzled byte col

  auto STAGE = [&](int nb_, int kt) {
#pragma unroll
    for (int j = 0; j < 2; ++j) {
      async16(A + (size_t)(m0 + j * 32 + arow) * K + kt + (acolb >> 1),
              (char*)&As[nb_][0] + j * 4096 + wid * 1024);
      async16(W + (size_t)(n0 + j * 32 + arow) * K + kt + (acolb >> 1),
              (char*)&Bs[nb_][0] + j * 4096 + wid * 1024);
    }
  };

  STAGE(0, 0);
  __syncthreads();
  int cur = 0;

  for (int kt = 0; kt < K; kt += 64) {
    if (kt + 64 < K) STAGE(cur ^ 1, kt + 64);
#pragma unroll
    for (int kk = 0; kk < 2; ++kk) {
      short8 af[2], bf[2];
#pragma unroll
      for (int mt = 0; mt < 2; ++mt)
        af[mt] = *(const short8*)((const char*)&As[cur][0] + (wr * 32 + mt * 16 + sr) * 128 +
                                  ((kk * 64 + g * 16) ^ sws));
#pragma unroll
      for (int nt = 0; nt < 2; ++nt)
        bf[nt] = *(const short8*)((const char*)&Bs[cur][0] + (wc * 32 + nt * 16 + sr) * 128 +
                                  ((kk * 64 + g * 16) ^ sws));
#pragma unroll
      for (int mt = 0; mt < 2; ++mt)
#pragma unroll
        for (int nt = 0; nt < 2; ++nt)
          acc[mt][nt] = __builtin_amdgcn_mfma_f32_16x16x32_bf16(af[mt], bf[nt], acc[mt][nt], 0, 0, 0);
    }
    __syncthreads();
    cur ^= 1;
  }

#pragma unroll
  for (int nt = 0; nt < 2; ++nt) {
    const int col = n0 + wc * 32 + nt * 16 + sr;
    const float bv = bias[col];
#pragma unroll
    for (int mt = 0; mt < 2; ++mt)
#pragma unroll
      for (int r = 0; r < 4; ++r) {
        const int row = m0 + wr * 32 + mt * 16 + g * 4 + r;
        C[(size_t)row * N + col] = acc[mt][nt][r] + bv;
      }
  }
}

// ---------------------------------------------------------------------------
// V transpose: Vh (S,B,D) bf16 -> VT[bh][dk][t]  (shape [32][64][2048])
// ---------------------------------------------------------------------------
__global__ __launch_bounds__(256) void vtrans_kernel(const u16* __restrict__ Vh,
                                                     u16* __restrict__ VT) {
  __shared__ u16 tl[4096];   // [t][dk] linear
  const int tid = threadIdx.x;
  const int w = tid >> 6;
  const int t0 = blockIdx.x * 64;
  const int bh = blockIdx.y;
  const int b = bh >> 4, h = bh & 15;
  const int str = tid >> 3;
  const int scc = (tid & 7) * 8;
#pragma unroll
  for (int it = 0; it < 2; ++it)
    async16(Vh + (size_t)((t0 + str + it * 32) * 2 + b) * 1024 + h * 64 + scc,
            (char*)tl + it * 4096 + w * 1024);
  __syncthreads();
  const int dk = tid >> 2;
  const int t4 = (tid & 3) * 16;
  short8 ov[2];
#pragma unroll
  for (int half = 0; half < 2; ++half)
#pragma unroll
    for (int j = 0; j < 8; ++j)
      ov[half][j] = (short)tl[(t4 + half * 8 + j) * 64 + dk];
  u16* dst = VT + (size_t)(bh * 64 + dk) * 2048 + t0 + t4;
  *(short8*)dst = ov[0];
  *(short8*)(dst + 8) = ov[1];
}

// ---------------------------------------------------------------------------
// Flash attention v8 (best found): 32x32x16 MFMA, pair-staged KV.  Grid 512
// flat (XCD-swizzled), 256 thr = 4 waves, wave owns 32 q-rows.  TWO 64-row
// KV tiles staged per barrier (4 LDS buffers, 64 KB); both processed between
// barriers for ILP.  Swapped QK^T (A=K, B=Q, 0.125*log2e in Wq); C/D col=q=
// lane&31, row t=(r&3)+8*(r>>2)+4*(lane>>5) [m74/m101].  P->PV A-frags via
// cvt_pk + permlane32_swap builtin.  No-max softmax, l reduced at end.
// ---------------------------------------------------------------------------
__global__ __launch_bounds__(256, 2) void attn8_kernel(const u16* __restrict__ Q,
                                                       const u16* __restrict__ K,
                                                       const u16* __restrict__ VT,
                                                       const float* __restrict__ mask,
                                                       const int* __restrict__ maskflag,
                                                       u16* __restrict__ O) {
  __shared__ u16 Kl[2][2][4096];   // [buf][subtile][t 0..63][d 0..63], swizzled
  __shared__ u16 Vl[2][2][4096];   // [buf][subtile][d 0..63][t 0..63], swizzled

  const int tid = threadIdx.x;
  const int lane = tid & 63;
  const int w = tid >> 6;
  const int ln = lane & 31;     // col within 32-block
  const int hi = lane >> 5;     // lane half
  const int sw = (ln & 7) << 4;

  // T1: cluster the 16 q-blocks of each bh on one XCD (512 = 8 XCDs x 64)
  const int flat = blockIdx.x;
  const int virt = ((flat & 7) << 6) | (flat >> 3);
  const int qi = virt & 15;
  const int bh = virt >> 4;
  const int q0 = qi * 128 + w * 32;
  const int b = bh >> 4, h = bh & 15;
  const int usemask = *maskflag;

  const u16* Qb = Q + b * DM + h * DKH;
  const u16* Kb = K + b * DM + h * DKH;
  const u16* VTb = VT + (size_t)bh * 64 * 2048;

  // Q fragments (B-operand 32x32x16: col n=q=ln, k = ks*16 + hi*8 + j)
  short8 aq[4];
#pragma unroll
  for (int ks = 0; ks < 4; ++ks)
    aq[ks] = *(const short8*)&Qb[(size_t)(q0 + ln) * 2048 + ks * 16 + hi * 8];

  f32x16 acc[2] = {};
  float l_ = 0.f;
  const float L2E = 1.44269504088896f;

  const int strow = tid >> 3;                                   // 0..31
  const int scb = (((tid & 7) * 16) ^ ((strow & 7) << 4)) >> 1; // pre-swizzled col (elems)

  auto STAGE = [&](int nb, int t0n) {   // stages rows [t0n, t0n+128)
#pragma unroll
    for (int st = 0; st < 2; ++st)
#pragma unroll
      for (int it = 0; it < 2; ++it) {
        async16(Kb + (size_t)(t0n + st * 64 + strow + it * 32) * 2048 + scb,
                (char*)&Kl[nb][st][0] + it * 4096 + w * 1024);
        async16(VTb + (size_t)(strow + it * 32) * 2048 + t0n + st * 64 + scb,
                (char*)&Vl[nb][st][0] + it * 4096 + w * 1024);
      }
  };

  STAGE(0, 0);
  __syncthreads();
  int cur = 0;

  for (int tp = 0; tp < SEQ; tp += 128) {
    if (tp + 128 < SEQ) STAGE(cur ^ 1, tp + 128);

#pragma unroll
    for (int st = 0; st < 2; ++st) {
      const int t0 = tp + st * 64;

      // K fragments (A-operand: row t = tb*32+ln, k = d = ks*16+hi*8+j)
      short8 kf[2][4];
#pragma unroll
      for (int tb = 0; tb < 2; ++tb)
#pragma unroll
        for (int ks = 0; ks < 4; ++ks)
          kf[tb][ks] = *(const short8*)((const char*)&Kl[cur][st][0] +
                                        (tb * 32 + ln) * 128 + ((ks * 32 + hi * 16) ^ sw));

      // S'^T (log2 units): 2 blocks of 32t x 32q
      f32x16 sc[2] = {};
      __builtin_amdgcn_s_setprio(1);
#pragma unroll
      for (int tb = 0; tb < 2; ++tb)
#pragma unroll
        for (int ks = 0; ks < 4; ++ks)
          sc[tb] = __builtin_amdgcn_mfma_f32_32x32x16_bf16(kf[tb][ks], aq[ks], sc[tb], 0, 0, 0);
      __builtin_amdgcn_s_setprio(0);

      // V^T fragments (B-operand: col n=d=db*32+ln, k = t = ks*16+hi*8+j)
      short8 vf[2][4];
#pragma unroll
      for (int db = 0; db < 2; ++db)
#pragma unroll
        for (int ks = 0; ks < 4; ++ks)
          vf[db][ks] = *(const short8*)((const char*)&Vl[cur][st][0] +
                                        (db * 32 + ln) * 128 + ((ks * 32 + hi * 16) ^ sw));

      // no-max softmax + in-register P redistribution (cvt_pk + permlane32_swap)
      short8 pa[4];
      float rs = 0.f;
#pragma unroll
      for (int tb = 0; tb < 2; ++tb) {
        float p[16];
#pragma unroll
        for (int r = 0; r < 16; ++r) {
          float xv = sc[tb][r];
          if (usemask)
            xv = __builtin_fmaf(
                mask[(size_t)(q0 + ln) * SEQ + t0 + tb * 32 + (r & 3) + 8 * (r >> 2) + 4 * hi],
                L2E, xv);
          p[r] = EXP2(xv);
          rs += p[r];
        }
#pragma unroll
        for (int ksl = 0; ksl < 2; ++ksl) {
          unsigned int c0 = cvtpk_bf16(p[8 * ksl + 0], p[8 * ksl + 1]);  // (t0,t1 | t4,t5)
          unsigned int c1 = cvtpk_bf16(p[8 * ksl + 2], p[8 * ksl + 3]);  // (t2,t3 | t6,t7)
          unsigned int c4 = cvtpk_bf16(p[8 * ksl + 4], p[8 * ksl + 5]);  // (t8,t9 | t12,t13)
          unsigned int c5 = cvtpk_bf16(p[8 * ksl + 6], p[8 * ksl + 7]);  // (t10,t11|t14,t15)
          permswap(c0, c4);   // c0 -> dword0; c4 -> dword2
          permswap(c1, c5);   // c1 -> dword1; c5 -> dword3
          union { uint4v u; short8 s; } cc;
          cc.u[0] = c0; cc.u[1] = c1; cc.u[2] = c4; cc.u[3] = c5;
          pa[tb * 2 + ksl] = cc.s;
        }
      }
      l_ += rs;

      // PV: O[q][d] += P[q][t] V[t][d]
      __builtin_amdgcn_s_setprio(1);
#pragma unroll
      for (int ks = 0; ks < 4; ++ks)
#pragma unroll
        for (int db = 0; db < 2; ++db)
          acc[db] = __builtin_amdgcn_mfma_f32_32x32x16_bf16(pa[ks], vf[db][ks], acc[db], 0, 0, 0);
      __builtin_amdgcn_s_setprio(0);
    }

    __syncthreads();
    cur ^= 1;
  }

  // final l reduction (halves) + normalize + write
  l_ += __shfl_xor(l_, 32);
  const float linv = 1.f / l_;
  float lb[16];
#pragma unroll
  for (int r = 0; r < 16; ++r)
    lb[r] = __shfl(linv, (r & 3) + 8 * (r >> 2) + 4 * hi);
  const size_t obase = (size_t)b * DM + h * DKH;
#pragma unroll
  for (int db = 0; db < 2; ++db)
#pragma unroll
    for (int r = 0; r < 16; ++r) {
      const int q = q0 + (r & 3) + 8 * (r >> 2) + 4 * hi;
      O[(size_t)q * 2048 + obase + db * 32 + ln] = f2bf(acc[db][r] * lb[r]);
    }
}

// ---------------------------------------------------------------------------
// Launch
// ---------------------------------------------------------------------------
extern "C" void kernel_launch(void* const* d_in, const int* in_sizes, int n_in,
                              void* d_out, int out_size, void* d_ws, size_t ws_size,
                              hipStream_t stream) {
  const float* q = (const float*)d_in[0];
  const float* k = (const float*)d_in[1];
  const float* v = (const float*)d_in[2];
  const float* msk = (const float*)d_in[3];
  const float* Wq = (const float*)d_in[4];
  const float* bq = (const float*)d_in[5];
  const float* Wk = (const float*)d_in[6];
  const float* bk = (const float*)d_in[7];
  const float* Wv = (const float*)d_in[8];
  const float* bv = (const float*)d_in[9];
  const float* Wo = (const float*)d_in[10];
  const float* bo = (const float*)d_in[11];
  float* out = (float*)d_out;

  char* ws = (char*)d_ws;
  const size_t SZX = (size_t)MROWS * DM * 2;   // 8 MB bf16 activation
  const size_t SZW = (size_t)DM * DM * 2;      // 2 MB bf16 weight
  u16* Wqb = (u16*)(ws + 3 * SZX + 0 * SZW);
  u16* Wkb = (u16*)(ws + 3 * SZX + 1 * SZW);
  u16* Wvb = (u16*)(ws + 3 * SZX + 2 * SZW);
  u16* Wob = (u16*)(ws + 3 * SZX + 3 * SZW);
  u16* Qh  = (u16*)(ws + 3 * SZX + 4 * SZW + 0 * SZX);
  u16* Kh  = (u16*)(ws + 3 * SZX + 4 * SZW + 1 * SZX);
  u16* Vh  = (u16*)(ws + 3 * SZX + 4 * SZW + 2 * SZX);
  u16* AO  = (u16*)(ws + 3 * SZX + 4 * SZW + 3 * SZX);
  int* flag = (int*)(ws + 7 * SZX + 4 * SZW);
  u16* VTg = (u16*)(ws + 0 * SZX);   // free region (old qb slot)

  hipMemsetAsync(flag, 0, 4, stream);

  // fold softmax scale AND log2(e) into Wq/bq: S' = (QK^T)/8 * log2e
  const float QS = 0.125f * 1.44269504088896f;

  CvtArgs ca = {};
  ca.s[0] = Wq; ca.d[0] = Wqb; ca.n[0] = DM * DM;    ca.scale[0] = QS;
  ca.s[1] = Wk; ca.d[1] = Wkb; ca.n[1] = DM * DM;    ca.scale[1] = 1.f;
  ca.s[2] = Wv; ca.d[2] = Wvb; ca.n[2] = DM * DM;    ca.scale[2] = 1.f;
  ca.s[3] = Wo; ca.d[3] = Wob; ca.n[3] = DM * DM;    ca.scale[3] = 1.f;
  ca.s[4] = msk; ca.d[4] = nullptr; ca.n[4] = SEQ * SEQ; ca.scale[4] = 1.f;
  ca.flag = flag;
  cvt_kernel<<<dim3(1024, 5, 1), 256, 0, stream>>>(ca);

  QkvArgs gp;
  gp.A[0] = q; gp.W[0] = Wqb; gp.bias[0] = bq; gp.bscale[0] = QS;  gp.C[0] = Qh;
  gp.A[1] = k; gp.W[1] = Wkb; gp.bias[1] = bk; gp.bscale[1] = 1.f; gp.C[1] = Kh;
  gp.A[2] = v; gp.W[2] = Wvb; gp.bias[2] = bv; gp.bscale[2] = 1.f; gp.C[2] = Vh;
  gemm_qkvf_kernel<<<dim3(64, 8, 3), 256, 0, stream>>>(gp, MROWS, DM, DM);

  vtrans_kernel<<<dim3(32, 32, 1), 256, 0, stream>>>(Vh, VTg);

  attn8_kernel<<<dim3(512, 1, 1), 256, 0, stream>>>(Qh, Kh, VTg, msk, flag, AO);

  gemm_f32_kernel<<<dim3(64, 16, 1), 256, 0, stream>>>(AO, Wob, bo, out, MROWS, DM, DM);
}

// Round 18
// 139.002 us; speedup vs baseline: 1.0154x; 1.0146x over previous
//
#include <hip/hip_runtime.h>

// ---------------------------------------------------------------------------
// MultiHeadAttention forward, MI355X/gfx950.
// cvt(all fp32->bf16 + mask scan) -> QKV proj (bf16 MFMA, 64x128 tiles,
// 6 blocks/CU, XOR-swizzled LDS) -> V transpose -> flash attn v8 (32x32
// MFMA, permlane32_swap builtin, pair-staged KV) -> out proj (64x64,
// XOR-swizzled LDS, 4+ blocks/CU).
// Ledger: fused fp32-A qkv (r13-r17) loses to this split: fp32 A-tiles halve
// staging intensity; block-rotation is the binding lever for these GEMMs.
// ---------------------------------------------------------------------------

#define DEV static __device__ __forceinline__

typedef unsigned short u16;
typedef __attribute__((ext_vector_type(8))) short short8;
typedef __attribute__((ext_vector_type(4))) float f32x4;
typedef __attribute__((ext_vector_type(16))) float f32x16;
typedef __attribute__((ext_vector_type(4))) unsigned short ushort4v;
typedef __attribute__((ext_vector_type(4))) unsigned int uint4v;
typedef __attribute__((ext_vector_type(2))) unsigned int uint2v;

#define SEQ   2048
#define BATCH 2
#define DM    1024
#define NH    16
#define DKH   64
#define MROWS (SEQ*BATCH)   // 4096

DEV u16 f2bf(float f) {            // RNE
  union { float f; unsigned int u; } v; v.f = f;
  unsigned int u = v.u;
  return (u16)((u + 0x7FFFu + ((u >> 16) & 1u)) >> 16);
}

DEV unsigned int cvtpk_bf16(float lo, float hi) {  // dword = bf16(hi)<<16 | bf16(lo), RNE
  unsigned int r;
  asm("v_cvt_pk_bf16_f32 %0, %1, %2" : "=v"(r) : "v"(lo), "v"(hi));
  return r;
}

// swap a.lanes[32:63] <-> b.lanes[0:31] via BUILTIN (hazard-modeled; raw asm
// caused intermittent stale-register reads, r14).
#if __has_builtin(__builtin_amdgcn_permlane32_swap)
DEV void permswap(unsigned int& a, unsigned int& b) {
  uint2v r = __builtin_amdgcn_permlane32_swap(a, b, false, false);
  a = r[0]; b = r[1];
}
#else
DEV void permswap(unsigned int& a, unsigned int& b) {
  asm volatile("s_nop 1\n\tv_permlane32_swap_b32 %0, %1\n\ts_nop 1"
               : "+v"(a), "+v"(b));
}
#endif

#if __has_builtin(__builtin_amdgcn_exp2f)
#define EXP2(x) __builtin_amdgcn_exp2f(x)
#else
#define EXP2(x) exp2f(x)
#endif

// async global->LDS, 16B per lane. LDS dest is wave-uniform base + lane*16.
DEV void async16(const void* g, void* l) {
  __builtin_amdgcn_global_load_lds(
      (const __attribute__((address_space(1))) unsigned int*)g,
      (__attribute__((address_space(3))) unsigned int*)l, 16, 0, 0);
}

// ---------------------------------------------------------------------------
// fp32 -> bf16 conversion (8 slots; d==nullptr entry = mask-zero scan)
// ---------------------------------------------------------------------------
struct CvtArgs {
  const float* s[8];
  u16* d[8];
  int n[8];
  float scale[8];
  int* flag;
};

__global__ __launch_bounds__(256) void cvt_kernel(CvtArgs a) {
  const int t = blockIdx.y;
  const int n = a.n[t];
  const int stride = 1024 * 256 * 4;
  if (a.d[t] == nullptr) {   // mask scan
    const float* __restrict__ m = a.s[t];
    int any = 0;
    for (int i = (blockIdx.x * 256 + threadIdx.x) * 4; i < n; i += stride) {
      f32x4 v = *(const f32x4*)&m[i];
      any |= (v[0] != 0.f); any |= (v[1] != 0.f);
      any |= (v[2] != 0.f); any |= (v[3] != 0.f);
    }
    if (any) atomicOr(a.flag, 1);
    return;
  }
  const float* __restrict__ s = a.s[t];
  u16* __restrict__ d = a.d[t];
  const float sc = a.scale[t];
  for (int i = (blockIdx.x * 256 + threadIdx.x) * 4; i < n; i += stride) {
    f32x4 f = *(const f32x4*)&s[i];
    ushort4v o;
    o[0] = f2bf(f[0] * sc); o[1] = f2bf(f[1] * sc);
    o[2] = f2bf(f[2] * sc); o[3] = f2bf(f[3] * sc);
    *(ushort4v*)&d[i] = o;
  }
}

// ---------------------------------------------------------------------------
// QKV GEMM: C[M,N] = A[M,K] @ W[N,K]^T + bias*bscale (all bf16 in, bf16 out).
// 64x128 tiles (MT=2, NT=4), BK=64, single-buffer, 24 KB LDS -> 6 blocks/CU,
// grid (64,8,3)=1536.  Both tiles XOR-swizzled both-sides (rule #21).
// ---------------------------------------------------------------------------
struct QkvArgs {
  const u16* A[3];
  const u16* W[3];
  const float* bias[3];
  float bscale[3];
  u16* C[3];
};

__global__ __launch_bounds__(256) void gemm_qkv_kernel(QkvArgs p, int M, int N, int K) {
  __shared__ u16 As[64 * 64];      // 8 KB bf16 A tile, 128B rows, swizzled
  __shared__ u16 Bs[128 * 64];     // 16 KB bf16 W tile, 128B rows, swizzled
  const int z = blockIdx.z;
  const u16* __restrict__ A = p.A[z];
  const u16* __restrict__ W = p.W[z];
  const int fl = blockIdx.x + 64 * blockIdx.y;
  const int virt = (fl & 7) * 64 + (fl >> 3);
  const int mb = virt >> 3, nb = virt & 7;
  const int m0 = mb * 64, n0 = nb * 128;

  const int tid = threadIdx.x;
  const int lane = tid & 63;
  const int wid = tid >> 6;
  const int wr = wid >> 1, wc = wid & 1;
  const int sr = lane & 15, g = lane >> 4;
  const int sws = (sr & 7) << 4;     // fragment-read swizzle

  f32x4 acc[2][4] = {};

  // staging: 32 rows x 128B subtiles, swizzled source col
  const int arow = tid >> 3;                                  // 0..31
  const int acolb = ((tid & 7) * 16) ^ ((arow & 7) << 4);     // swizzled byte col

  for (int kt = 0; kt < K; kt += 64) {
#pragma unroll
    for (int j = 0; j < 2; ++j)
      async16(A + (size_t)(m0 + j * 32 + arow) * K + kt + (acolb >> 1),
              (char*)As + j * 4096 + wid * 1024);
#pragma unroll
    for (int j = 0; j < 4; ++j)
      async16(W + (size_t)(n0 + j * 32 + arow) * K + kt + (acolb >> 1),
              (char*)Bs + j * 4096 + wid * 1024);
    __syncthreads();
#pragma unroll
    for (int kk = 0; kk < 2; ++kk) {
      short8 af[2], bf[4];
#pragma unroll
      for (int mt = 0; mt < 2; ++mt)
        af[mt] = *(const short8*)((const char*)As + (wr * 32 + mt * 16 + sr) * 128 +
                                  ((kk * 64 + g * 16) ^ sws));
#pragma unroll
      for (int nt = 0; nt < 4; ++nt)
        bf[nt] = *(const short8*)((const char*)Bs + (wc * 64 + nt * 16 + sr) * 128 +
                                  ((kk * 64 + g * 16) ^ sws));
#pragma unroll
      for (int mt = 0; mt < 2; ++mt)
#pragma unroll
        for (int nt = 0; nt < 4; ++nt)
          acc[mt][nt] = __builtin_amdgcn_mfma_f32_16x16x32_bf16(af[mt], bf[nt], acc[mt][nt], 0, 0, 0);
    }
    __syncthreads();
  }

  // C/D layout: row=(lane>>4)*4+reg, col=lane&15  [m89-verified]
  const float* __restrict__ bias = p.bias[z];
  const float bscale = p.bscale[z];
  u16* __restrict__ C = p.C[z];
#pragma unroll
  for (int nt = 0; nt < 4; ++nt) {
    const int col = n0 + wc * 64 + nt * 16 + sr;
    const float bv = bias[col] * bscale;
#pragma unroll
    for (int mt = 0; mt < 2; ++mt)
#pragma unroll
      for (int r = 0; r < 4; ++r) {
        const int row = m0 + wr * 32 + mt * 16 + g * 4 + r;
        C[(size_t)row * N + col] = f2bf(acc[mt][nt][r] + bv);
      }
  }
}

// ---------------------------------------------------------------------------
// Out-proj GEMM (bf16 A x bf16 W^T -> fp32 + bias).  64x64 tiles (MT=NT=2),
// grid 1024, single-buffer 16 KB LDS, XOR-swizzled tiles.  (r15: ~13 us)
// ---------------------------------------------------------------------------
__global__ __launch_bounds__(256) void gemm_f32_kernel(const u16* __restrict__ A,
                                                       const u16* __restrict__ W,
                                                       const float* __restrict__ bias,
                                                       float* __restrict__ C,
                                                       int M, int N, int K) {
  __shared__ u16 As[64 * 64];
  __shared__ u16 Bs[64 * 64];
  const int fl = blockIdx.x + 64 * blockIdx.y;
  const int virt = (fl & 7) * 128 + (fl >> 3);
  const int mb = virt >> 4, nb = virt & 15;
  const int m0 = mb * 64, n0 = nb * 64;

  const int tid = threadIdx.x;
  const int lane = tid & 63;
  const int wid = tid >> 6;
  const int wr = wid >> 1, wc = wid & 1;
  const int sr = lane & 15, g = lane >> 4;
  const int sws = (sr & 7) << 4;

  f32x4 acc[2][2] = {};

  const int arow = tid >> 3;                                  // 0..31
  const int acolb = ((tid & 7) * 16) ^ ((arow & 7) << 4);     // swizzled byte col

  for (int kt = 0; kt < K; kt += 64) {
#pragma unroll
    for (int j = 0; j < 2; ++j) {
      async16(A + (size_t)(m0 + j * 32 + arow) * K + kt + (acolb >> 1),
              (char*)As + j * 4096 + wid * 1024);
      async16(W + (size_t)(n0 + j * 32 + arow) * K + kt + (acolb >> 1),
              (char*)Bs + j * 4096 + wid * 1024);
    }
    __syncthreads();
#pragma unroll
    for (int kk = 0; kk < 2; ++kk) {
      short8 af[2], bf[2];
#pragma unroll
      for (int mt = 0; mt < 2; ++mt)
        af[mt] = *(const short8*)((const char*)As + (wr * 32 + mt * 16 + sr) * 128 +
                                  ((kk * 64 + g * 16) ^ sws));
#pragma unroll
      for (int nt = 0; nt < 2; ++nt)
        bf[nt] = *(const short8*)((const char*)Bs + (wc * 32 + nt * 16 + sr) * 128 +
                                  ((kk * 64 + g * 16) ^ sws));
#pragma unroll
      for (int mt = 0; mt < 2; ++mt)
#pragma unroll
        for (int nt = 0; nt < 2; ++nt)
          acc[mt][nt] = __builtin_amdgcn_mfma_f32_16x16x32_bf16(af[mt], bf[nt], acc[mt][nt], 0, 0, 0);
    }
    __syncthreads();
  }

#pragma unroll
  for (int nt = 0; nt < 2; ++nt) {
    const int col = n0 + wc * 32 + nt * 16 + sr;
    const float bv = bias[col];
#pragma unroll
    for (int mt = 0; mt < 2; ++mt)
#pragma unroll
      for (int r = 0; r < 4; ++r) {
        const int row = m0 + wr * 32 + mt * 16 + g * 4 + r;
        C[(size_t)row * N + col] = acc[mt][nt][r] + bv;
      }
  }
}

// ---------------------------------------------------------------------------
// V transpose: Vh (S,B,D) bf16 -> VT[bh][dk][t]  (shape [32][64][2048])
// ---------------------------------------------------------------------------
__global__ __launch_bounds__(256) void vtrans_kernel(const u16* __restrict__ Vh,
                                                     u16* __restrict__ VT) {
  __shared__ u16 tl[4096];   // [t][dk] linear
  const int tid = threadIdx.x;
  const int w = tid >> 6;
  const int t0 = blockIdx.x * 64;
  const int bh = blockIdx.y;
  const int b = bh >> 4, h = bh & 15;
  const int str = tid >> 3;
  const int scc = (tid & 7) * 8;
#pragma unroll
  for (int it = 0; it < 2; ++it)
    async16(Vh + (size_t)((t0 + str + it * 32) * 2 + b) * 1024 + h * 64 + scc,
            (char*)tl + it * 4096 + w * 1024);
  __syncthreads();
  const int dk = tid >> 2;
  const int t4 = (tid & 3) * 16;
  short8 ov[2];
#pragma unroll
  for (int half = 0; half < 2; ++half)
#pragma unroll
    for (int j = 0; j < 8; ++j)
      ov[half][j] = (short)tl[(t4 + half * 8 + j) * 64 + dk];
  u16* dst = VT + (size_t)(bh * 64 + dk) * 2048 + t0 + t4;
  *(short8*)dst = ov[0];
  *(short8*)(dst + 8) = ov[1];
}

// ---------------------------------------------------------------------------
// Flash attention v8 (best found): 32x32x16 MFMA, pair-staged KV.  Grid 512
// flat (XCD-swizzled), 256 thr = 4 waves, wave owns 32 q-rows.  TWO 64-row
// KV tiles staged per barrier (4 LDS buffers, 64 KB); both processed between
// barriers for ILP.  Swapped QK^T (A=K, B=Q, 0.125*log2e in Wq); C/D col=q=
// lane&31, row t=(r&3)+8*(r>>2)+4*(lane>>5) [m74/m101].  P->PV A-frags via
// cvt_pk + permlane32_swap builtin.  No-max softmax, l reduced at end.
// ---------------------------------------------------------------------------
__global__ __launch_bounds__(256, 2) void attn8_kernel(const u16* __restrict__ Q,
                                                       const u16* __restrict__ K,
                                                       const u16* __restrict__ VT,
                                                       const float* __restrict__ mask,
                                                       const int* __restrict__ maskflag,
                                                       u16* __restrict__ O) {
  __shared__ u16 Kl[2][2][4096];   // [buf][subtile][t 0..63][d 0..63], swizzled
  __shared__ u16 Vl[2][2][4096];   // [buf][subtile][d 0..63][t 0..63], swizzled

  const int tid = threadIdx.x;
  const int lane = tid & 63;
  const int w = tid >> 6;
  const int ln = lane & 31;     // col within 32-block
  const int hi = lane >> 5;     // lane half
  const int sw = (ln & 7) << 4;

  // T1: cluster the 16 q-blocks of each bh on one XCD (512 = 8 XCDs x 64)
  const int flat = blockIdx.x;
  const int virt = ((flat & 7) << 6) | (flat >> 3);
  const int qi = virt & 15;
  const int bh = virt >> 4;
  const int q0 = qi * 128 + w * 32;
  const int b = bh >> 4, h = bh & 15;
  const int usemask = *maskflag;

  const u16* Qb = Q + b * DM + h * DKH;
  const u16* Kb = K + b * DM + h * DKH;
  const u16* VTb = VT + (size_t)bh * 64 * 2048;

  // Q fragments (B-operand 32x32x16: col n=q=ln, k = ks*16 + hi*8 + j)
  short8 aq[4];
#pragma unroll
  for (int ks = 0; ks < 4; ++ks)
    aq[ks] = *(const short8*)&Qb[(size_t)(q0 + ln) * 2048 + ks * 16 + hi * 8];

  f32x16 acc[2] = {};
  float l_ = 0.f;
  const float L2E = 1.44269504088896f;

  const int strow = tid >> 3;                                   // 0..31
  const int scb = (((tid & 7) * 16) ^ ((strow & 7) << 4)) >> 1; // pre-swizzled col (elems)

  auto STAGE = [&](int nb, int t0n) {   // stages rows [t0n, t0n+128)
#pragma unroll
    for (int st = 0; st < 2; ++st)
#pragma unroll
      for (int it = 0; it < 2; ++it) {
        async16(Kb + (size_t)(t0n + st * 64 + strow + it * 32) * 2048 + scb,
                (char*)&Kl[nb][st][0] + it * 4096 + w * 1024);
        async16(VTb + (size_t)(strow + it * 32) * 2048 + t0n + st * 64 + scb,
                (char*)&Vl[nb][st][0] + it * 4096 + w * 1024);
      }
  };

  STAGE(0, 0);
  __syncthreads();
  int cur = 0;

  for (int tp = 0; tp < SEQ; tp += 128) {
    if (tp + 128 < SEQ) STAGE(cur ^ 1, tp + 128);

#pragma unroll
    for (int st = 0; st < 2; ++st) {
      const int t0 = tp + st * 64;

      // K fragments (A-operand: row t = tb*32+ln, k = d = ks*16+hi*8+j)
      short8 kf[2][4];
#pragma unroll
      for (int tb = 0; tb < 2; ++tb)
#pragma unroll
        for (int ks = 0; ks < 4; ++ks)
          kf[tb][ks] = *(const short8*)((const char*)&Kl[cur][st][0] +
                                        (tb * 32 + ln) * 128 + ((ks * 32 + hi * 16) ^ sw));

      // S'^T (log2 units): 2 blocks of 32t x 32q
      f32x16 sc[2] = {};
      __builtin_amdgcn_s_setprio(1);
#pragma unroll
      for (int tb = 0; tb < 2; ++tb)
#pragma unroll
        for (int ks = 0; ks < 4; ++ks)
          sc[tb] = __builtin_amdgcn_mfma_f32_32x32x16_bf16(kf[tb][ks], aq[ks], sc[tb], 0, 0, 0);
      __builtin_amdgcn_s_setprio(0);

      // V^T fragments (B-operand: col n=d=db*32+ln, k = t = ks*16+hi*8+j)
      short8 vf[2][4];
#pragma unroll
      for (int db = 0; db < 2; ++db)
#pragma unroll
        for (int ks = 0; ks < 4; ++ks)
          vf[db][ks] = *(const short8*)((const char*)&Vl[cur][st][0] +
                                        (db * 32 + ln) * 128 + ((ks * 32 + hi * 16) ^ sw));

      // no-max softmax + in-register P redistribution (cvt_pk + permlane32_swap)
      short8 pa[4];
      float rs = 0.f;
#pragma unroll
      for (int tb = 0; tb < 2; ++tb) {
        float p[16];
#pragma unroll
        for (int r = 0; r < 16; ++r) {
          float xv = sc[tb][r];
          if (usemask)
            xv = __builtin_fmaf(
                mask[(size_t)(q0 + ln) * SEQ + t0 + tb * 32 + (r & 3) + 8 * (r >> 2) + 4 * hi],
                L2E, xv);
          p[r] = EXP2(xv);
          rs += p[r];
        }
#pragma unroll
        for (int ksl = 0; ksl < 2; ++ksl) {
          unsigned int c0 = cvtpk_bf16(p[8 * ksl + 0], p[8 * ksl + 1]);  // (t0,t1 | t4,t5)
          unsigned int c1 = cvtpk_bf16(p[8 * ksl + 2], p[8 * ksl + 3]);  // (t2,t3 | t6,t7)
          unsigned int c4 = cvtpk_bf16(p[8 * ksl + 4], p[8 * ksl + 5]);  // (t8,t9 | t12,t13)
          unsigned int c5 = cvtpk_bf16(p[8 * ksl + 6], p[8 * ksl + 7]);  // (t10,t11|t14,t15)
          permswap(c0, c4);   // c0 -> dword0; c4 -> dword2
          permswap(c1, c5);   // c1 -> dword1; c5 -> dword3
          union { uint4v u; short8 s; } cc;
          cc.u[0] = c0; cc.u[1] = c1; cc.u[2] = c4; cc.u[3] = c5;
          pa[tb * 2 + ksl] = cc.s;
        }
      }
      l_ += rs;

      // PV: O[q][d] += P[q][t] V[t][d]
      __builtin_amdgcn_s_setprio(1);
#pragma unroll
      for (int ks = 0; ks < 4; ++ks)
#pragma unroll
        for (int db = 0; db < 2; ++db)
          acc[db] = __builtin_amdgcn_mfma_f32_32x32x16_bf16(pa[ks], vf[db][ks], acc[db], 0, 0, 0);
      __builtin_amdgcn_s_setprio(0);
    }

    __syncthreads();
    cur ^= 1;
  }

  // final l reduction (halves) + normalize + write
  l_ += __shfl_xor(l_, 32);
  const float linv = 1.f / l_;
  float lb[16];
#pragma unroll
  for (int r = 0; r < 16; ++r)
    lb[r] = __shfl(linv, (r & 3) + 8 * (r >> 2) + 4 * hi);
  const size_t obase = (size_t)b * DM + h * DKH;
#pragma unroll
  for (int db = 0; db < 2; ++db)
#pragma unroll
    for (int r = 0; r < 16; ++r) {
      const int q = q0 + (r & 3) + 8 * (r >> 2) + 4 * hi;
      O[(size_t)q * 2048 + obase + db * 32 + ln] = f2bf(acc[db][r] * lb[r]);
    }
}

// ---------------------------------------------------------------------------
// Launch
// ---------------------------------------------------------------------------
extern "C" void kernel_launch(void* const* d_in, const int* in_sizes, int n_in,
                              void* d_out, int out_size, void* d_ws, size_t ws_size,
                              hipStream_t stream) {
  const float* q = (const float*)d_in[0];
  const float* k = (const float*)d_in[1];
  const float* v = (const float*)d_in[2];
  const float* msk = (const float*)d_in[3];
  const float* Wq = (const float*)d_in[4];
  const float* bq = (const float*)d_in[5];
  const float* Wk = (const float*)d_in[6];
  const float* bk = (const float*)d_in[7];
  const float* Wv = (const float*)d_in[8];
  const float* bv = (const float*)d_in[9];
  const float* Wo = (const float*)d_in[10];
  const float* bo = (const float*)d_in[11];
  float* out = (float*)d_out;

  char* ws = (char*)d_ws;
  const size_t SZX = (size_t)MROWS * DM * 2;   // 8 MB bf16 activation
  const size_t SZW = (size_t)DM * DM * 2;      // 2 MB bf16 weight
  u16* qb  = (u16*)(ws + 0 * SZX);
  u16* kb  = (u16*)(ws + 1 * SZX);
  u16* vb  = (u16*)(ws + 2 * SZX);
  u16* Wqb = (u16*)(ws + 3 * SZX + 0 * SZW);
  u16* Wkb = (u16*)(ws + 3 * SZX + 1 * SZW);
  u16* Wvb = (u16*)(ws + 3 * SZX + 2 * SZW);
  u16* Wob = (u16*)(ws + 3 * SZX + 3 * SZW);
  u16* Qh  = (u16*)(ws + 3 * SZX + 4 * SZW + 0 * SZX);
  u16* Kh  = (u16*)(ws + 3 * SZX + 4 * SZW + 1 * SZX);
  u16* Vh  = (u16*)(ws + 3 * SZX + 4 * SZW + 2 * SZX);
  u16* AO  = (u16*)(ws + 3 * SZX + 4 * SZW + 3 * SZX);
  int* flag = (int*)(ws + 7 * SZX + 4 * SZW);
  u16* VTg = qb;   // reuse qb (dead after gemm_qkv)

  hipMemsetAsync(flag, 0, 4, stream);

  // fold softmax scale AND log2(e) into Wq/bq: S' = (QK^T)/8 * log2e
  const float QS = 0.125f * 1.44269504088896f;

  CvtArgs ca = {};
  ca.s[0] = q;  ca.d[0] = qb;  ca.n[0] = MROWS * DM; ca.scale[0] = 1.f;
  ca.s[1] = k;  ca.d[1] = kb;  ca.n[1] = MROWS * DM; ca.scale[1] = 1.f;
  ca.s[2] = v;  ca.d[2] = vb;  ca.n[2] = MROWS * DM; ca.scale[2] = 1.f;
  ca.s[3] = Wq; ca.d[3] = Wqb; ca.n[3] = DM * DM;    ca.scale[3] = QS;
  ca.s[4] = Wk; ca.d[4] = Wkb; ca.n[4] = DM * DM;    ca.scale[4] = 1.f;
  ca.s[5] = Wv; ca.d[5] = Wvb; ca.n[5] = DM * DM;    ca.scale[5] = 1.f;
  ca.s[6] = Wo; ca.d[6] = Wob; ca.n[6] = DM * DM;    ca.scale[6] = 1.f;
  ca.s[7] = msk; ca.d[7] = nullptr; ca.n[7] = SEQ * SEQ; ca.scale[7] = 1.f;
  ca.flag = flag;
  cvt_kernel<<<dim3(1024, 8, 1), 256, 0, stream>>>(ca);

  QkvArgs gp;
  gp.A[0] = qb; gp.W[0] = Wqb; gp.bias[0] = bq; gp.bscale[0] = QS;  gp.C[0] = Qh;
  gp.A[1] = kb; gp.W[1] = Wkb; gp.bias[1] = bk; gp.bscale[1] = 1.f; gp.C[1] = Kh;
  gp.A[2] = vb; gp.W[2] = Wvb; gp.bias[2] = bv; gp.bscale[2] = 1.f; gp.C[2] = Vh;
  gemm_qkv_kernel<<<dim3(64, 8, 3), 256, 0, stream>>>(gp, MROWS, DM, DM);

  vtrans_kernel<<<dim3(32, 32, 1), 256, 0, stream>>>(Vh, VTg);

  attn8_kernel<<<dim3(512, 1, 1), 256, 0, stream>>>(Qh, Kh, VTg, msk, flag, AO);

  gemm_f32_kernel<<<dim3(64, 16, 1), 256, 0, stream>>>(AO, Wob, bo, out, MROWS, DM, DM);
}

// Round 19
// 130.121 us; speedup vs baseline: 1.0847x; 1.0683x over previous
//
#include <hip/hip_runtime.h>

// ---------------------------------------------------------------------------
// MultiHeadAttention forward, MI355X/gfx950.  (= round-15 best: 132.2 us)
// cvt(weights only + mask scan) -> QKV proj FUSED fp32-A (bf16 MFMA, cvt_pk
// at fragment read, 64x128 tiles, XOR-swizzled LDS) -> V transpose -> flash
// attn v8 (32x32 MFMA, permlane P-redistribution via BUILTIN permlane32_swap
// [hazard-modeled], pair-staged KV) -> out proj (64x64, XOR-swizzled LDS).
// ---------------------------------------------------------------------------

#define DEV static __device__ __forceinline__

typedef unsigned short u16;
typedef __attribute__((ext_vector_type(8))) short short8;
typedef __attribute__((ext_vector_type(4))) float f32x4;
typedef __attribute__((ext_vector_type(16))) float f32x16;
typedef __attribute__((ext_vector_type(4))) unsigned short ushort4v;
typedef __attribute__((ext_vector_type(4))) unsigned int uint4v;
typedef __attribute__((ext_vector_type(2))) unsigned int uint2v;

#define SEQ   2048
#define BATCH 2
#define DM    1024
#define NH    16
#define DKH   64
#define MROWS (SEQ*BATCH)   // 4096

DEV u16 f2bf(float f) {            // RNE
  union { float f; unsigned int u; } v; v.f = f;
  unsigned int u = v.u;
  return (u16)((u + 0x7FFFu + ((u >> 16) & 1u)) >> 16);
}

DEV unsigned int cvtpk_bf16(float lo, float hi) {  // dword = bf16(hi)<<16 | bf16(lo), RNE
  unsigned int r;
  asm("v_cvt_pk_bf16_f32 %0, %1, %2" : "=v"(r) : "v"(lo), "v"(hi));
  return r;
}

// swap a.lanes[32:63] <-> b.lanes[0:31].  Use the BUILTIN so the compiler's
// hazard recognizer models the permlane instruction (VALU-write -> permlane
// read wait states).  Raw asm hid it -> intermittent stale-register reads
// (r14 post-timing divergence).  Fallback asm carries explicit s_nop.
#if __has_builtin(__builtin_amdgcn_permlane32_swap)
DEV void permswap(unsigned int& a, unsigned int& b) {
  uint2v r = __builtin_amdgcn_permlane32_swap(a, b, false, false);
  a = r[0]; b = r[1];
}
#else
DEV void permswap(unsigned int& a, unsigned int& b) {
  asm volatile("s_nop 1\n\tv_permlane32_swap_b32 %0, %1\n\ts_nop 1"
               : "+v"(a), "+v"(b));
}
#endif

#if __has_builtin(__builtin_amdgcn_exp2f)
#define EXP2(x) __builtin_amdgcn_exp2f(x)
#else
#define EXP2(x) exp2f(x)
#endif

// async global->LDS, 16B per lane. LDS dest is wave-uniform base + lane*16.
DEV void async16(const void* g, void* l) {
  __builtin_amdgcn_global_load_lds(
      (const __attribute__((address_space(1))) unsigned int*)g,
      (__attribute__((address_space(3))) unsigned int*)l, 16, 0, 0);
}

// ---------------------------------------------------------------------------
// fp32 -> bf16 conversion: weights only (d==nullptr entry = mask-zero scan)
// ---------------------------------------------------------------------------
struct CvtArgs {
  const float* s[8];
  u16* d[8];
  int n[8];
  float scale[8];
  int* flag;
};

__global__ __launch_bounds__(256) void cvt_kernel(CvtArgs a) {
  const int t = blockIdx.y;
  const int n = a.n[t];
  const int stride = 1024 * 256 * 4;
  if (a.d[t] == nullptr) {   // mask scan
    const float* __restrict__ m = a.s[t];
    int any = 0;
    for (int i = (blockIdx.x * 256 + threadIdx.x) * 4; i < n; i += stride) {
      f32x4 v = *(const f32x4*)&m[i];
      any |= (v[0] != 0.f); any |= (v[1] != 0.f);
      any |= (v[2] != 0.f); any |= (v[3] != 0.f);
    }
    if (any) atomicOr(a.flag, 1);
    return;
  }
  const float* __restrict__ s = a.s[t];
  u16* __restrict__ d = a.d[t];
  const float sc = a.scale[t];
  for (int i = (blockIdx.x * 256 + threadIdx.x) * 4; i < n; i += stride) {
    f32x4 f = *(const f32x4*)&s[i];
    ushort4v o;
    o[0] = f2bf(f[0] * sc); o[1] = f2bf(f[1] * sc);
    o[2] = f2bf(f[2] * sc); o[3] = f2bf(f[3] * sc);
    *(ushort4v*)&d[i] = o;
  }
}

// ---------------------------------------------------------------------------
// Fused QKV GEMM: C[M,N] = bf16(A_f32)[M,K] @ W[N,K]^T + bias*bscale.
// A staged fp32 via global_load_lds (256B rows), W bf16 (128B rows); BOTH
// tiles XOR-swizzled (pre-swizzled global source + swizzled fragment read,
// rule #21) -> 2-way bank conflicts (free).  cvt_pk at A-fragment read.
// 64x128 tiles, 4 waves 2x2, BK=64, 32 KB LDS (5 blocks/CU).
// ---------------------------------------------------------------------------
struct QkvArgs {
  const float* A[3];
  const u16* W[3];
  const float* bias[3];
  float bscale[3];
  u16* C[3];
};

__global__ __launch_bounds__(256) void gemm_qkvf_kernel(QkvArgs p, int M, int N, int K) {
  __shared__ float Asf[64 * 64];   // 16 KB fp32 A tile, 256B rows, swizzled
  __shared__ u16 Bs[128 * 64];     // 16 KB bf16 W tile, 128B rows, swizzled
  const int z = blockIdx.z;
  const float* __restrict__ A = p.A[z];
  const u16* __restrict__ W = p.W[z];
  const int fl = blockIdx.x + 64 * blockIdx.y;
  const int virt = (fl & 7) * 64 + (fl >> 3);
  const int mb = virt >> 3, nb = virt & 7;
  const int m0 = mb * 64, n0 = nb * 128;

  const int tid = threadIdx.x;
  const int lane = tid & 63;
  const int wid = tid >> 6;
  const int wr = wid >> 1, wc = wid & 1;
  const int sr = lane & 15, g = lane >> 4;
  const int sws = (sr & 7) << 4;     // fragment-read swizzle

  f32x4 acc[2][4] = {};

  // A staging: subtile = 16 rows x 256B; flat byte = it*4096 + tid*16
  const int arow_a = tid >> 4;                                   // 0..15
  const int acolb_a = ((tid & 15) * 16) ^ ((arow_a & 7) << 4);   // swizzled byte col
  // B staging: subtile = 32 rows x 128B
  const int brow = tid >> 3;                                     // 0..31
  const int bcolb = ((tid & 7) * 16) ^ ((brow & 7) << 4);

  for (int kt = 0; kt < K; kt += 64) {
#pragma unroll
    for (int it = 0; it < 4; ++it)
      async16(A + (size_t)(m0 + it * 16 + arow_a) * K + kt + (acolb_a >> 2),
              (char*)Asf + it * 4096 + wid * 1024);
#pragma unroll
    for (int j = 0; j < 4; ++j)
      async16(W + (size_t)(n0 + j * 32 + brow) * K + kt + (bcolb >> 1),
              (char*)Bs + j * 4096 + wid * 1024);
    __syncthreads();
#pragma unroll
    for (int kk = 0; kk < 2; ++kk) {
      short8 af[2], bf[4];
#pragma unroll
      for (int mt = 0; mt < 2; ++mt) {
        const char* ap = (const char*)Asf + (wr * 32 + mt * 16 + sr) * 256;
        const int c0 = kk * 128 + g * 32;
        f32x4 a0 = *(const f32x4*)(ap + (c0 ^ sws));
        f32x4 a1 = *(const f32x4*)(ap + ((c0 + 16) ^ sws));
        union { uint4v u; short8 s; } ca_;
        ca_.u[0] = cvtpk_bf16(a0[0], a0[1]);
        ca_.u[1] = cvtpk_bf16(a0[2], a0[3]);
        ca_.u[2] = cvtpk_bf16(a1[0], a1[1]);
        ca_.u[3] = cvtpk_bf16(a1[2], a1[3]);
        af[mt] = ca_.s;
      }
#pragma unroll
      for (int nt = 0; nt < 4; ++nt)
        bf[nt] = *(const short8*)((const char*)Bs + (wc * 64 + nt * 16 + sr) * 128 +
                                  ((kk * 64 + g * 16) ^ sws));
#pragma unroll
      for (int mt = 0; mt < 2; ++mt)
#pragma unroll
        for (int nt = 0; nt < 4; ++nt)
          acc[mt][nt] = __builtin_amdgcn_mfma_f32_16x16x32_bf16(af[mt], bf[nt], acc[mt][nt], 0, 0, 0);
    }
    __syncthreads();
  }

  // C/D layout: row=(lane>>4)*4+reg, col=lane&15  [m89-verified]
  const float* __restrict__ bias = p.bias[z];
  const float bscale = p.bscale[z];
  u16* __restrict__ C = p.C[z];
#pragma unroll
  for (int nt = 0; nt < 4; ++nt) {
    const int col = n0 + wc * 64 + nt * 16 + sr;
    const float bv = bias[col] * bscale;
#pragma unroll
    for (int mt = 0; mt < 2; ++mt)
#pragma unroll
      for (int r = 0; r < 4; ++r) {
        const int row = m0 + wr * 32 + mt * 16 + g * 4 + r;
        C[(size_t)row * N + col] = f2bf(acc[mt][nt][r] + bv);
      }
  }
}

// ---------------------------------------------------------------------------
// Out-proj GEMM (bf16 A x bf16 W^T -> fp32 + bias).  64x64 tiles (MT=NT=2),
// grid 1024 = 4 blocks/CU, 16 KB LDS, XOR-swizzled tiles.
// ---------------------------------------------------------------------------
__global__ __launch_bounds__(256) void gemm_f32_kernel(const u16* __restrict__ A,
                                                       const u16* __restrict__ W,
                                                       const float* __restrict__ bias,
                                                       float* __restrict__ C,
                                                       int M, int N, int K) {
  __shared__ u16 As[64 * 64];
  __shared__ u16 Bs[64 * 64];
  const int fl = blockIdx.x + 64 * blockIdx.y;
  const int virt = (fl & 7) * 128 + (fl >> 3);
  const int mb = virt >> 4, nb = virt & 15;
  const int m0 = mb * 64, n0 = nb * 64;

  const int tid = threadIdx.x;
  const int lane = tid & 63;
  const int wid = tid >> 6;
  const int wr = wid >> 1, wc = wid & 1;
  const int sr = lane & 15, g = lane >> 4;
  const int sws = (sr & 7) << 4;

  f32x4 acc[2][2] = {};

  const int arow = tid >> 3;                                  // 0..31
  const int acolb = ((tid & 7) * 16) ^ ((arow & 7) << 4);     // swizzled byte col

  for (int kt = 0; kt < K; kt += 64) {
#pragma unroll
    for (int j = 0; j < 2; ++j) {
      async16(A + (size_t)(m0 + j * 32 + arow) * K + kt + (acolb >> 1),
              (char*)As + j * 4096 + wid * 1024);
      async16(W + (size_t)(n0 + j * 32 + arow) * K + kt + (acolb >> 1),
              (char*)Bs + j * 4096 + wid * 1024);
    }
    __syncthreads();
#pragma unroll
    for (int kk = 0; kk < 2; ++kk) {
      short8 af[2], bf[2];
#pragma unroll
      for (int mt = 0; mt < 2; ++mt)
        af[mt] = *(const short8*)((const char*)As + (wr * 32 + mt * 16 + sr) * 128 +
                                  ((kk * 64 + g * 16) ^ sws));
#pragma unroll
      for (int nt = 0; nt < 2; ++nt)
        bf[nt] = *(const short8*)((const char*)Bs + (wc * 32 + nt * 16 + sr) * 128 +
                                  ((kk * 64 + g * 16) ^ sws));
#pragma unroll
      for (int mt = 0; mt < 2; ++mt)
#pragma unroll
        for (int nt = 0; nt < 2; ++nt)
          acc[mt][nt] = __builtin_amdgcn_mfma_f32_16x16x32_bf16(af[mt], bf[nt], acc[mt][nt], 0, 0, 0);
    }
    __syncthreads();
  }

#pragma unroll
  for (int nt = 0; nt < 2; ++nt) {
    const int col = n0 + wc * 32 + nt * 16 + sr;
    const float bv = bias[col];
#pragma unroll
    for (int mt = 0; mt < 2; ++mt)
#pragma unroll
      for (int r = 0; r < 4; ++r) {
        const int row = m0 + wr * 32 + mt * 16 + g * 4 + r;
        C[(size_t)row * N + col] = acc[mt][nt][r] + bv;
      }
  }
}

// ---------------------------------------------------------------------------
// V transpose: Vh (S,B,D) bf16 -> VT[bh][dk][t]  (shape [32][64][2048])
// ---------------------------------------------------------------------------
__global__ __launch_bounds__(256) void vtrans_kernel(const u16* __restrict__ Vh,
                                                     u16* __restrict__ VT) {
  __shared__ u16 tl[4096];   // [t][dk] linear
  const int tid = threadIdx.x;
  const int w = tid >> 6;
  const int t0 = blockIdx.x * 64;
  const int bh = blockIdx.y;
  const int b = bh >> 4, h = bh & 15;
  const int str = tid >> 3;
  const int scc = (tid & 7) * 8;
#pragma unroll
  for (int it = 0; it < 2; ++it)
    async16(Vh + (size_t)((t0 + str + it * 32) * 2 + b) * 1024 + h * 64 + scc,
            (char*)tl + it * 4096 + w * 1024);
  __syncthreads();
  const int dk = tid >> 2;
  const int t4 = (tid & 3) * 16;
  short8 ov[2];
#pragma unroll
  for (int half = 0; half < 2; ++half)
#pragma unroll
    for (int j = 0; j < 8; ++j)
      ov[half][j] = (short)tl[(t4 + half * 8 + j) * 64 + dk];
  u16* dst = VT + (size_t)(bh * 64 + dk) * 2048 + t0 + t4;
  *(short8*)dst = ov[0];
  *(short8*)(dst + 8) = ov[1];
}

// ---------------------------------------------------------------------------
// Flash attention v8 (best found): 32x32x16 MFMA, pair-staged KV.  Grid 512
// flat (XCD-swizzled), 256 thr = 4 waves, wave owns 32 q-rows.  TWO 64-row
// KV tiles staged per barrier (4 LDS buffers, 64 KB); both processed between
// barriers for ILP.  Swapped QK^T (A=K, B=Q, 0.125*log2e in Wq); C/D col=q=
// lane&31, row t=(r&3)+8*(r>>2)+4*(lane>>5) [m74/m101].  P->PV A-frags via
// cvt_pk + permlane32_swap builtin.  No-max softmax, l reduced at end.
// ---------------------------------------------------------------------------
__global__ __launch_bounds__(256, 2) void attn8_kernel(const u16* __restrict__ Q,
                                                       const u16* __restrict__ K,
                                                       const u16* __restrict__ VT,
                                                       const float* __restrict__ mask,
                                                       const int* __restrict__ maskflag,
                                                       u16* __restrict__ O) {
  __shared__ u16 Kl[2][2][4096];   // [buf][subtile][t 0..63][d 0..63], swizzled
  __shared__ u16 Vl[2][2][4096];   // [buf][subtile][d 0..63][t 0..63], swizzled

  const int tid = threadIdx.x;
  const int lane = tid & 63;
  const int w = tid >> 6;
  const int ln = lane & 31;     // col within 32-block
  const int hi = lane >> 5;     // lane half
  const int sw = (ln & 7) << 4;

  // T1: cluster the 16 q-blocks of each bh on one XCD (512 = 8 XCDs x 64)
  const int flat = blockIdx.x;
  const int virt = ((flat & 7) << 6) | (flat >> 3);
  const int qi = virt & 15;
  const int bh = virt >> 4;
  const int q0 = qi * 128 + w * 32;
  const int b = bh >> 4, h = bh & 15;
  const int usemask = *maskflag;

  const u16* Qb = Q + b * DM + h * DKH;
  const u16* Kb = K + b * DM + h * DKH;
  const u16* VTb = VT + (size_t)bh * 64 * 2048;

  // Q fragments (B-operand 32x32x16: col n=q=ln, k = ks*16 + hi*8 + j)
  short8 aq[4];
#pragma unroll
  for (int ks = 0; ks < 4; ++ks)
    aq[ks] = *(const short8*)&Qb[(size_t)(q0 + ln) * 2048 + ks * 16 + hi * 8];

  f32x16 acc[2] = {};
  float l_ = 0.f;
  const float L2E = 1.44269504088896f;

  const int strow = tid >> 3;                                   // 0..31
  const int scb = (((tid & 7) * 16) ^ ((strow & 7) << 4)) >> 1; // pre-swizzled col (elems)

  auto STAGE = [&](int nb, int t0n) {   // stages rows [t0n, t0n+128)
#pragma unroll
    for (int st = 0; st < 2; ++st)
#pragma unroll
      for (int it = 0; it < 2; ++it) {
        async16(Kb + (size_t)(t0n + st * 64 + strow + it * 32) * 2048 + scb,
                (char*)&Kl[nb][st][0] + it * 4096 + w * 1024);
        async16(VTb + (size_t)(strow + it * 32) * 2048 + t0n + st * 64 + scb,
                (char*)&Vl[nb][st][0] + it * 4096 + w * 1024);
      }
  };

  STAGE(0, 0);
  __syncthreads();
  int cur = 0;

  for (int tp = 0; tp < SEQ; tp += 128) {
    if (tp + 128 < SEQ) STAGE(cur ^ 1, tp + 128);

#pragma unroll
    for (int st = 0; st < 2; ++st) {
      const int t0 = tp + st * 64;

      // K fragments (A-operand: row t = tb*32+ln, k = d = ks*16+hi*8+j)
      short8 kf[2][4];
#pragma unroll
      for (int tb = 0; tb < 2; ++tb)
#pragma unroll
        for (int ks = 0; ks < 4; ++ks)
          kf[tb][ks] = *(const short8*)((const char*)&Kl[cur][st][0] +
                                        (tb * 32 + ln) * 128 + ((ks * 32 + hi * 16) ^ sw));

      // S'^T (log2 units): 2 blocks of 32t x 32q
      f32x16 sc[2] = {};
      __builtin_amdgcn_s_setprio(1);
#pragma unroll
      for (int tb = 0; tb < 2; ++tb)
#pragma unroll
        for (int ks = 0; ks < 4; ++ks)
          sc[tb] = __builtin_amdgcn_mfma_f32_32x32x16_bf16(kf[tb][ks], aq[ks], sc[tb], 0, 0, 0);
      __builtin_amdgcn_s_setprio(0);

      // V^T fragments (B-operand: col n=d=db*32+ln, k = t = ks*16+hi*8+j)
      short8 vf[2][4];
#pragma unroll
      for (int db = 0; db < 2; ++db)
#pragma unroll
        for (int ks = 0; ks < 4; ++ks)
          vf[db][ks] = *(const short8*)((const char*)&Vl[cur][st][0] +
                                        (db * 32 + ln) * 128 + ((ks * 32 + hi * 16) ^ sw));

      // no-max softmax + in-register P redistribution (cvt_pk + permlane32_swap)
      short8 pa[4];
      float rs = 0.f;
#pragma unroll
      for (int tb = 0; tb < 2; ++tb) {
        float p[16];
#pragma unroll
        for (int r = 0; r < 16; ++r) {
          float xv = sc[tb][r];
          if (usemask)
            xv = __builtin_fmaf(
                mask[(size_t)(q0 + ln) * SEQ + t0 + tb * 32 + (r & 3) + 8 * (r >> 2) + 4 * hi],
                L2E, xv);
          p[r] = EXP2(xv);
          rs += p[r];
        }
#pragma unroll
        for (int ksl = 0; ksl < 2; ++ksl) {
          unsigned int c0 = cvtpk_bf16(p[8 * ksl + 0], p[8 * ksl + 1]);  // (t0,t1 | t4,t5)
          unsigned int c1 = cvtpk_bf16(p[8 * ksl + 2], p[8 * ksl + 3]);  // (t2,t3 | t6,t7)
          unsigned int c4 = cvtpk_bf16(p[8 * ksl + 4], p[8 * ksl + 5]);  // (t8,t9 | t12,t13)
          unsigned int c5 = cvtpk_bf16(p[8 * ksl + 6], p[8 * ksl + 7]);  // (t10,t11|t14,t15)
          permswap(c0, c4);   // c0 -> dword0; c4 -> dword2
          permswap(c1, c5);   // c1 -> dword1; c5 -> dword3
          union { uint4v u; short8 s; } cc;
          cc.u[0] = c0; cc.u[1] = c1; cc.u[2] = c4; cc.u[3] = c5;
          pa[tb * 2 + ksl] = cc.s;
        }
      }
      l_ += rs;

      // PV: O[q][d] += P[q][t] V[t][d]
      __builtin_amdgcn_s_setprio(1);
#pragma unroll
      for (int ks = 0; ks < 4; ++ks)
#pragma unroll
        for (int db = 0; db < 2; ++db)
          acc[db] = __builtin_amdgcn_mfma_f32_32x32x16_bf16(pa[ks], vf[db][ks], acc[db], 0, 0, 0);
      __builtin_amdgcn_s_setprio(0);
    }

    __syncthreads();
    cur ^= 1;
  }

  // final l reduction (halves) + normalize + write
  l_ += __shfl_xor(l_, 32);
  const float linv = 1.f / l_;
  float lb[16];
#pragma unroll
  for (int r = 0; r < 16; ++r)
    lb[r] = __shfl(linv, (r & 3) + 8 * (r >> 2) + 4 * hi);
  const size_t obase = (size_t)b * DM + h * DKH;
#pragma unroll
  for (int db = 0; db < 2; ++db)
#pragma unroll
    for (int r = 0; r < 16; ++r) {
      const int q = q0 + (r & 3) + 8 * (r >> 2) + 4 * hi;
      O[(size_t)q * 2048 + obase + db * 32 + ln] = f2bf(acc[db][r] * lb[r]);
    }
}

// ---------------------------------------------------------------------------
// Launch
// ---------------------------------------------------------------------------
extern "C" void kernel_launch(void* const* d_in, const int* in_sizes, int n_in,
                              void* d_out, int out_size, void* d_ws, size_t ws_size,
                              hipStream_t stream) {
  const float* q = (const float*)d_in[0];
  const float* k = (const float*)d_in[1];
  const float* v = (const float*)d_in[2];
  const float* msk = (const float*)d_in[3];
  const float* Wq = (const float*)d_in[4];
  const float* bq = (const float*)d_in[5];
  const float* Wk = (const float*)d_in[6];
  const float* bk = (const float*)d_in[7];
  const float* Wv = (const float*)d_in[8];
  const float* bv = (const float*)d_in[9];
  const float* Wo = (const float*)d_in[10];
  const float* bo = (const float*)d_in[11];
  float* out = (float*)d_out;

  char* ws = (char*)d_ws;
  const size_t SZX = (size_t)MROWS * DM * 2;   // 8 MB bf16 activation
  const size_t SZW = (size_t)DM * DM * 2;      // 2 MB bf16 weight
  u16* Wqb = (u16*)(ws + 3 * SZX + 0 * SZW);
  u16* Wkb = (u16*)(ws + 3 * SZX + 1 * SZW);
  u16* Wvb = (u16*)(ws + 3 * SZX + 2 * SZW);
  u16* Wob = (u16*)(ws + 3 * SZX + 3 * SZW);
  u16* Qh  = (u16*)(ws + 3 * SZX + 4 * SZW + 0 * SZX);
  u16* Kh  = (u16*)(ws + 3 * SZX + 4 * SZW + 1 * SZX);
  u16* Vh  = (u16*)(ws + 3 * SZX + 4 * SZW + 2 * SZX);
  u16* AO  = (u16*)(ws + 3 * SZX + 4 * SZW + 3 * SZX);
  int* flag = (int*)(ws + 7 * SZX + 4 * SZW);
  u16* VTg = (u16*)(ws + 0 * SZX);   // free region (old qb slot)

  hipMemsetAsync(flag, 0, 4, stream);

  // fold softmax scale AND log2(e) into Wq/bq: S' = (QK^T)/8 * log2e
  const float QS = 0.125f * 1.44269504088896f;

  CvtArgs ca = {};
  ca.s[0] = Wq; ca.d[0] = Wqb; ca.n[0] = DM * DM;    ca.scale[0] = QS;
  ca.s[1] = Wk; ca.d[1] = Wkb; ca.n[1] = DM * DM;    ca.scale[1] = 1.f;
  ca.s[2] = Wv; ca.d[2] = Wvb; ca.n[2] = DM * DM;    ca.scale[2] = 1.f;
  ca.s[3] = Wo; ca.d[3] = Wob; ca.n[3] = DM * DM;    ca.scale[3] = 1.f;
  ca.s[4] = msk; ca.d[4] = nullptr; ca.n[4] = SEQ * SEQ; ca.scale[4] = 1.f;
  ca.flag = flag;
  cvt_kernel<<<dim3(1024, 5, 1), 256, 0, stream>>>(ca);

  QkvArgs gp;
  gp.A[0] = q; gp.W[0] = Wqb; gp.bias[0] = bq; gp.bscale[0] = QS;  gp.C[0] = Qh;
  gp.A[1] = k; gp.W[1] = Wkb; gp.bias[1] = bk; gp.bscale[1] = 1.f; gp.C[1] = Kh;
  gp.A[2] = v; gp.W[2] = Wvb; gp.bias[2] = bv; gp.bscale[2] = 1.f; gp.C[2] = Vh;
  gemm_qkvf_kernel<<<dim3(64, 8, 3), 256, 0, stream>>>(gp, MROWS, DM, DM);

  vtrans_kernel<<<dim3(32, 32, 1), 256, 0, stream>>>(Vh, VTg);

  attn8_kernel<<<dim3(512, 1, 1), 256, 0, stream>>>(Qh, Kh, VTg, msk, flag, AO);

  gemm_f32_kernel<<<dim3(64, 16, 1), 256, 0, stream>>>(AO, Wob, bo, out, MROWS, DM, DM);
}